// Round 8
// baseline (689.806 us; speedup 1.0000x reference)
//
#include <hip/hip_runtime.h>
#include <math.h>

#define B_ 2
#define S_ 4096
#define HID_ 2048
#define H_ 16
#define KV_ 4
#define HD_ 128
#define K_ 1024
#define GROUPS_ 4
#define SCALE_ 0.08838834764831845f

typedef __bf16 bf16x8 __attribute__((ext_vector_type(8)));
typedef float f32x4 __attribute__((ext_vector_type(4)));
typedef float f32x8 __attribute__((ext_vector_type(8)));
typedef float f32x16 __attribute__((ext_vector_type(16)));
typedef ushort u16x8 __attribute__((ext_vector_type(8)));

__device__ __forceinline__ ushort f2bf(float f) {
  union { float f; unsigned int u; } x; x.f = f;
  unsigned int u = x.u;
  u += 0x7FFFu + ((u >> 16) & 1u);
  return (ushort)(u >> 16);
}
__device__ __forceinline__ float bf2f(ushort s) {
  union { unsigned int u; float f; } x; x.u = ((unsigned int)s) << 16;
  return x.f;
}

// async global->LDS, 16B per lane; LDS dest = uniform base + lane*16 [m97/m104]
__device__ __forceinline__ void gld16(const ushort* g, ushort* l) {
  __builtin_amdgcn_global_load_lds((const __attribute__((address_space(1))) void*)g,
                                   (__attribute__((address_space(3))) void*)l, 16, 0, 0);
}

// ---------------- elementwise cast fp32 -> bf16 ----------------
__global__ void cast_f32_bf16(const float* __restrict__ in, ushort* __restrict__ out, long n) {
  long i = ((long)blockIdx.x * blockDim.x + threadIdx.x) * 4;
  if (i >= n) return;
  float4 v = *(const float4*)(in + i);
  ushort4 o;
  o.x = f2bf(v.x); o.y = f2bf(v.y); o.z = f2bf(v.z); o.w = f2bf(v.w);
  *(ushort4*)(out + i) = o;
}

// ---------------- ALL fp32->bf16 weight transposes in ONE launch ----------------
__global__ void transpose_all(const float* __restrict__ Wq, const float* __restrict__ Wk,
                              const float* __restrict__ Wv, const float* __restrict__ Wo,
                              const float* __restrict__ E, const float* __restrict__ Fp,
                              ushort* __restrict__ WqkvT, ushort* __restrict__ WoT,
                              ushort* __restrict__ E_T, ushort* __restrict__ Fp_T) {
  __shared__ float t[32][33];
  int id = blockIdx.x;
  const float* src; ushort* dst; int R, C;
  if (id < 4096)       { src = Wq; dst = WqkvT;           R = 2048; C = 2048; }
  else if (id < 5120)  { src = Wk; dst = WqkvT + 4194304; R = 2048; C = 512;  id -= 4096; }
  else if (id < 6144)  { src = Wv; dst = WqkvT + 5242880; R = 2048; C = 512;  id -= 5120; }
  else if (id < 10240) { src = Wo; dst = WoT;             R = 2048; C = 2048; id -= 6144; }
  else if (id < 14336) { src = E;  dst = E_T;             R = 4096; C = 1024; id -= 10240; }
  else                 { src = Fp; dst = Fp_T;            R = 4096; C = 1024; id -= 14336; }
  int tX = C >> 5;
  int c0 = (id % tX) * 32, r0 = (id / tX) * 32;
  int tx = threadIdx.x, ty = threadIdx.y;
#pragma unroll
  for (int i = 0; i < 4; i++)
    t[ty + i * 8][tx] = src[(long)(r0 + ty + i * 8) * C + c0 + tx];
  __syncthreads();
#pragma unroll
  for (int i = 0; i < 4; i++)
    dst[(long)(c0 + ty + i * 8) * R + r0 + tx] = f2bf(t[tx][ty + i * 8]);
}

// ---------------- tiled transpose bf16, batched ----------------
__global__ void transpose_bf16(const ushort* __restrict__ in, ushort* __restrict__ out,
                               int R, int C, long sIn, long sOut) {
  __shared__ ushort t[32][34];
  in += (long)blockIdx.z * sIn;
  out += (long)blockIdx.z * sOut;
  int c0 = blockIdx.x * 32, r0 = blockIdx.y * 32;
  int tx = threadIdx.x, ty = threadIdx.y;
#pragma unroll
  for (int i = 0; i < 4; i++)
    t[ty + i * 8][tx] = in[(long)(r0 + ty + i * 8) * C + c0 + tx];
  __syncthreads();
#pragma unroll
  for (int i = 0; i < 4; i++)
    out[(long)(c0 + ty + i * 8) * R + r0 + tx] = t[tx][ty + i * 8];
}

// ---------------- RoPE + bias + layout, vectorized (short8/float8 per lane) ----------
// grid (24 heads, S/32, B); 8 lanes per row, each handles d = dt..dt+7 and d+64.
__global__ __launch_bounds__(256) void rope_qkv(
    const ushort* __restrict__ Cqkv,
    const float* __restrict__ bq, const float* __restrict__ bk,
    const float* __restrict__ bv,
    const float* __restrict__ cosp, const float* __restrict__ sinp,
    ushort* __restrict__ q_r, ushort* __restrict__ k_r, ushort* __restrict__ v_r) {
  int head = blockIdx.x;  // 0..23: 16 q heads, 4 k, 4 v
  int s = blockIdx.y * 32 + (threadIdx.x >> 3);
  int b = blockIdx.z;
  int dt = (threadIdx.x & 7) * 8;
  long cs = ((long)b * S_ + s) * HD_;
  f32x8 c1 = *(const f32x8*)(cosp + cs + dt);
  f32x8 c2 = *(const f32x8*)(cosp + cs + dt + 64);
  f32x8 s1 = *(const f32x8*)(sinp + cs + dt);
  f32x8 s2 = *(const f32x8*)(sinp + cs + dt + 64);
  long rowbase = ((long)b * S_ + s) * 3072;
  if (head < H_) {
    int h = head;
    long in = rowbase + h * HD_ + dt;
    u16x8 x1v = *(const u16x8*)(Cqkv + in);
    u16x8 x2v = *(const u16x8*)(Cqkv + in + 64);
    f32x8 b1 = *(const f32x8*)(bq + h * HD_ + dt);
    f32x8 b2 = *(const f32x8*)(bq + h * HD_ + dt + 64);
    u16x8 o1v, o2v;
#pragma unroll
    for (int j = 0; j < 8; j++) {
      float x1 = bf2f(x1v[j]) + b1[j];
      float x2 = bf2f(x2v[j]) + b2[j];
      o1v[j] = f2bf((x1 * c1[j] - x2 * s1[j]) * SCALE_);
      o2v[j] = f2bf((x2 * c2[j] + x1 * s2[j]) * SCALE_);
    }
    long ob = (((long)b * H_ + h) * S_ + s) * HD_ + dt;
    *(u16x8*)(q_r + ob) = o1v;
    *(u16x8*)(q_r + ob + 64) = o2v;
  } else if (head < H_ + KV_) {
    int kv = head - H_;
    long in = rowbase + 2048 + kv * HD_ + dt;
    u16x8 x1v = *(const u16x8*)(Cqkv + in);
    u16x8 x2v = *(const u16x8*)(Cqkv + in + 64);
    f32x8 b1 = *(const f32x8*)(bk + kv * HD_ + dt);
    f32x8 b2 = *(const f32x8*)(bk + kv * HD_ + dt + 64);
    u16x8 o1v, o2v;
#pragma unroll
    for (int j = 0; j < 8; j++) {
      float x1 = bf2f(x1v[j]) + b1[j];
      float x2 = bf2f(x2v[j]) + b2[j];
      o1v[j] = f2bf(x1 * c1[j] - x2 * s1[j]);
      o2v[j] = f2bf(x2 * c2[j] + x1 * s2[j]);
    }
    long ob = (((long)b * KV_ + kv) * S_ + s) * HD_ + dt;
    *(u16x8*)(k_r + ob) = o1v;
    *(u16x8*)(k_r + ob + 64) = o2v;
  } else {
    int kv = head - H_ - KV_;
    long in = rowbase + 2560 + kv * HD_ + dt;
    u16x8 x1v = *(const u16x8*)(Cqkv + in);
    u16x8 x2v = *(const u16x8*)(Cqkv + in + 64);
    f32x8 b1 = *(const f32x8*)(bv + kv * HD_ + dt);
    f32x8 b2 = *(const f32x8*)(bv + kv * HD_ + dt + 64);
    u16x8 o1v, o2v;
#pragma unroll
    for (int j = 0; j < 8; j++) {
      o1v[j] = f2bf(bf2f(x1v[j]) + b1[j]);
      o2v[j] = f2bf(bf2f(x2v[j]) + b2[j]);
    }
    long ob = (((long)b * KV_ + kv) * S_ + s) * HD_ + dt;
    *(u16x8*)(v_r + ob) = o1v;
    *(u16x8*)(v_r + ob + 64) = o2v;
  }
}

// ---------------- NT GEMM body (m97 structure + XOR swizzle) — kept for pkpv ----------------
template <int BM, int BN, bool OUT_BF16>
__device__ __forceinline__ void gemm_body(
    const ushort* __restrict__ Ab, const ushort* __restrict__ Bb, void* __restrict__ Cb,
    int bm, int bn, int k0, int k1, int ldA, int ldB, int ldC, float scale) {
  __shared__ alignas(16) ushort As[BM * 32];
  __shared__ alignas(16) ushort Bs[BN * 32];
  constexpr int MT = BM / 32, NT = BN / 32;
  const int tid = threadIdx.x;
  const int wv = tid >> 6, lane = tid & 63;
  const int quad = lane >> 4, l16 = lane & 15;
  const int wm = (wv >> 1) * (BM / 2);
  const int wn = (wv & 1) * (BN / 2);
  const int srow = lane >> 2;
  const int scp = lane & 3;
  f32x4 acc[MT][NT];
#pragma unroll
  for (int i = 0; i < MT; i++)
#pragma unroll
    for (int j = 0; j < NT; j++)
#pragma unroll
      for (int r = 0; r < 4; r++) acc[i][j][r] = 0.f;
  const int sw = quad ^ ((l16 >> 1) & 3);
  for (int kk = k0; kk < k1; kk += 32) {
    __syncthreads();
#pragma unroll
    for (int j = 0; j < BM / 64; j++) {
      int r0 = wv * (BM / 4) + j * 16;
      int row = r0 + srow;
      gld16(Ab + (long)(bm + row) * ldA + kk + (scp ^ ((row >> 1) & 3)) * 8, &As[r0 * 32]);
    }
#pragma unroll
    for (int j = 0; j < BN / 64; j++) {
      int r0 = wv * (BN / 4) + j * 16;
      int row = r0 + srow;
      gld16(Bb + (long)(bn + row) * ldB + kk + (scp ^ ((row >> 1) & 3)) * 8, &Bs[r0 * 32]);
    }
    __syncthreads();
    bf16x8 af[MT], bf[NT];
#pragma unroll
    for (int i = 0; i < MT; i++)
      af[i] = *(const bf16x8*)&As[(wm + i * 16 + l16) * 32 + sw * 8];
#pragma unroll
    for (int j = 0; j < NT; j++)
      bf[j] = *(const bf16x8*)&Bs[(wn + j * 16 + l16) * 32 + sw * 8];
#pragma unroll
    for (int i = 0; i < MT; i++)
#pragma unroll
      for (int j = 0; j < NT; j++)
        acc[i][j] = __builtin_amdgcn_mfma_f32_16x16x32_bf16(af[i], bf[j], acc[i][j], 0, 0, 0);
  }
#pragma unroll
  for (int i = 0; i < MT; i++)
#pragma unroll
    for (int j = 0; j < NT; j++)
#pragma unroll
      for (int r = 0; r < 4; r++) {
        long row = bm + wm + i * 16 + quad * 4 + r;
        long col = bn + wn + j * 16 + l16;
        float v = acc[i][j][r] * scale;
        if (OUT_BF16)
          ((ushort*)Cb)[row * ldC + col] = f2bf(v);
        else
          ((float*)Cb)[row * ldC + col] = v;
      }
}

// pk/pvT with split-K x4: fp32 partials. grid (8 tiles, 16 z, 4 kseg)
__global__ __launch_bounds__(256) void gemm_pkpv(
    const ushort* __restrict__ E_T, const ushort* __restrict__ k_rT,
    const ushort* __restrict__ v_rT, const ushort* __restrict__ Fp_T,
    float* __restrict__ part) {
  int z = blockIdx.y, ks = blockIdx.z;
  const ushort *A, *Bt;
  int bm, bn, ldC;
  if (z < 8) {  // pk[z] (K_,HD) = E_T @ k_rT[z]^T
    A = E_T; Bt = k_rT + (long)z * 524288;
    bm = blockIdx.x * 128; bn = 0; ldC = 128;
  } else {      // pvT[z-8] (HD,K_) = v_rT @ Fp_T^T
    A = v_rT + (long)(z - 8) * 524288; Bt = Fp_T;
    bm = 0; bn = blockIdx.x * 128; ldC = 1024;
  }
  float* Cb = part + (long)ks * 2097152 + (long)z * 131072;
  gemm_body<128, 128, false>(A, Bt, Cb, bm, bn, ks * 1024, ks * 1024 + 1024,
                             4096, 4096, ldC, 1.f);
}

// sum 4 fp32 partial slabs -> bf16 (pk||pvT contiguous)
__global__ void reduce4_bf16(const float* __restrict__ part, ushort* __restrict__ out) {
  long i = ((long)blockIdx.x * 256 + threadIdx.x) * 4;
  float4 a = *(const float4*)(part + i);
  float4 b = *(const float4*)(part + 2097152 + i);
  float4 c = *(const float4*)(part + 4194304 + i);
  float4 d = *(const float4*)(part + 6291456 + i);
  ushort4 o;
  o.x = f2bf(a.x + b.x + c.x + d.x);
  o.y = f2bf(a.y + b.y + c.y + d.y);
  o.z = f2bf(a.z + b.z + c.z + d.z);
  o.w = f2bf(a.w + b.w + c.w + d.w);
  *(ushort4*)(out + i) = o;
}

// ---------------- 256 x (NB*64) 8-phase NT GEMM (T2+T3+T4+T5), relaxed publish ----------
template <int NB, bool OUT_BF16>
__global__ __launch_bounds__(512, 2) void gemm8_nt(
    const ushort* __restrict__ Ab, const ushort* __restrict__ Bb, void* __restrict__ Cb,
    int ntn, int NT, int ldA, int ldB, int ldC) {
  __shared__ alignas(16) ushort As[2][256 * 64];        // 64 KB
  __shared__ alignas(16) ushort Bs[2][NB * 64 * 64];    // NB*16 KB
  const int nwg = gridDim.x;
  const int cpx = nwg >> 3;  // blocks per XCD (grids are %8==0)
  const int bid = blockIdx.x;
  const int swz = (bid & 7) * cpx + (bid >> 3);  // XCD-contiguous chunks (T1, bijective)
  const int bm = (swz / ntn) * 256, bn = (swz % ntn) * (NB * 64);
  const int tid = threadIdx.x;
  const int wv = tid >> 6, lane = tid & 63;
  const int quad = lane >> 4, l16 = lane & 15, l7 = l16 & 7;
  const int wm2 = wv >> 2, wn4 = wv & 3;
  const int ida = wn4;
  const int ha = wm2;
  const int lrow = lane >> 3, lchk = lane & 7;
  const int schk = (lchk ^ lrow) * 8;  // pre-swizzled source chunk (rule 21)

  auto stageBown = [&](int buf, int kt) {
#pragma unroll
    for (int j = 0; j < NB; j++) {
      int rloc = wn4 * (NB * 16) + j * 16 + wm2 * 8;
      int r = rloc + lrow;
      gld16(Bb + (long)(bn + r) * ldB + kt * 64 + schk, &Bs[buf][rloc * 64]);
    }
  };
  auto stageA = [&](int buf, int kt, int sp) {
#pragma unroll
    for (int j = 0; j < 2; j++) {
      int rloc = ha * 128 + sp * 64 + j * 32 + ida * 8;
      int r = rloc + lrow;
      gld16(Ab + (long)(bm + r) * ldA + kt * 64 + schk, &As[buf][rloc * 64]);
    }
  };
  auto rdA = [&](int buf, int m, int ks) -> bf16x8 {
    int ra = wm2 * 128 + m * 16 + l16;
    int c = (ks * 4 + quad) ^ l7;
    return *(const bf16x8*)&As[buf][ra * 64 + c * 8];
  };
  auto rdB = [&](int buf, int n, int ks) -> bf16x8 {
    int rb = wn4 * (NB * 16) + n * 16 + l16;
    int c = (ks * 4 + quad) ^ l7;
    return *(const bf16x8*)&Bs[buf][rb * 64 + c * 8];
  };

  f32x4 acc[8][NB];
#pragma unroll
  for (int m = 0; m < 8; m++)
#pragma unroll
    for (int n = 0; n < NB; n++)
#pragma unroll
      for (int r = 0; r < 4; r++) acc[m][n][r] = 0.f;

  stageBown(0, 0); stageA(0, 0, 0); stageA(0, 0, 1);
  asm volatile("s_waitcnt vmcnt(2)" ::: "memory");
  __builtin_amdgcn_s_barrier();

#pragma unroll 2
  for (int t = 0; t < NT - 1; ++t) {
    const int cur = t & 1, nxt = cur ^ 1;
    const int kt1 = t + 1;
    bf16x8 b[NB][2], x0[2], x1[2];
#pragma unroll
    for (int n = 0; n < NB; n++) { b[n][0] = rdB(cur, n, 0); b[n][1] = rdB(cur, n, 1); }
    x0[0] = rdA(cur, 0, 0); x0[1] = rdA(cur, 0, 1);
    x1[0] = rdA(cur, 1, 0); x1[1] = rdA(cur, 1, 1);
    stageBown(nxt, kt1);
    __builtin_amdgcn_s_barrier();
    asm volatile("s_waitcnt lgkmcnt(0)" ::: "memory");
    __builtin_amdgcn_s_setprio(1);
#pragma unroll
    for (int n = 0; n < NB; n++)
#pragma unroll
      for (int ks = 0; ks < 2; ks++) {
        acc[0][n] = __builtin_amdgcn_mfma_f32_16x16x32_bf16(x0[ks], b[n][ks], acc[0][n], 0, 0, 0);
        acc[1][n] = __builtin_amdgcn_mfma_f32_16x16x32_bf16(x1[ks], b[n][ks], acc[1][n], 0, 0, 0);
      }
    __builtin_amdgcn_s_setprio(0);
    __builtin_amdgcn_s_barrier();
    x0[0] = rdA(cur, 2, 0); x0[1] = rdA(cur, 2, 1);
    x1[0] = rdA(cur, 3, 0); x1[1] = rdA(cur, 3, 1);
    stageA(nxt, kt1, 0);
    if constexpr (NB == 3) asm volatile("s_waitcnt vmcnt(5)" ::: "memory");
    else                   asm volatile("s_waitcnt vmcnt(6)" ::: "memory");
    __builtin_amdgcn_s_barrier();
    asm volatile("s_waitcnt lgkmcnt(0)" ::: "memory");
    __builtin_amdgcn_s_setprio(1);
#pragma unroll
    for (int n = 0; n < NB; n++)
#pragma unroll
      for (int ks = 0; ks < 2; ks++) {
        acc[2][n] = __builtin_amdgcn_mfma_f32_16x16x32_bf16(x0[ks], b[n][ks], acc[2][n], 0, 0, 0);
        acc[3][n] = __builtin_amdgcn_mfma_f32_16x16x32_bf16(x1[ks], b[n][ks], acc[3][n], 0, 0, 0);
      }
    __builtin_amdgcn_s_setprio(0);
    __builtin_amdgcn_s_barrier();
    x0[0] = rdA(cur, 4, 0); x0[1] = rdA(cur, 4, 1);
    x1[0] = rdA(cur, 5, 0); x1[1] = rdA(cur, 5, 1);
    stageA(nxt, kt1, 1);
    __builtin_amdgcn_s_barrier();
    asm volatile("s_waitcnt lgkmcnt(0)" ::: "memory");
    __builtin_amdgcn_s_setprio(1);
#pragma unroll
    for (int n = 0; n < NB; n++)
#pragma unroll
      for (int ks = 0; ks < 2; ks++) {
        acc[4][n] = __builtin_amdgcn_mfma_f32_16x16x32_bf16(x0[ks], b[n][ks], acc[4][n], 0, 0, 0);
        acc[5][n] = __builtin_amdgcn_mfma_f32_16x16x32_bf16(x1[ks], b[n][ks], acc[5][n], 0, 0, 0);
      }
    __builtin_amdgcn_s_setprio(0);
    __builtin_amdgcn_s_barrier();
    x0[0] = rdA(cur, 6, 0); x0[1] = rdA(cur, 6, 1);
    x1[0] = rdA(cur, 7, 0); x1[1] = rdA(cur, 7, 1);
    asm volatile("s_waitcnt vmcnt(2)" ::: "memory");
    __builtin_amdgcn_s_barrier();
    asm volatile("s_waitcnt lgkmcnt(0)" ::: "memory");
    __builtin_amdgcn_s_setprio(1);
#pragma unroll
    for (int n = 0; n < NB; n++)
#pragma unroll
      for (int ks = 0; ks < 2; ks++) {
        acc[6][n] = __builtin_amdgcn_mfma_f32_16x16x32_bf16(x0[ks], b[n][ks], acc[6][n], 0, 0, 0);
        acc[7][n] = __builtin_amdgcn_mfma_f32_16x16x32_bf16(x1[ks], b[n][ks], acc[7][n], 0, 0, 0);
      }
    __builtin_amdgcn_s_setprio(0);
    __builtin_amdgcn_s_barrier();
  }

  {
    const int cur = (NT - 1) & 1;
    asm volatile("s_waitcnt vmcnt(0)" ::: "memory");
    __builtin_amdgcn_s_barrier();
    bf16x8 b[NB][2];
#pragma unroll
    for (int n = 0; n < NB; n++) { b[n][0] = rdB(cur, n, 0); b[n][1] = rdB(cur, n, 1); }
#pragma unroll
    for (int m = 0; m < 8; m++) {
      bf16x8 a0 = rdA(cur, m, 0), a1 = rdA(cur, m, 1);
#pragma unroll
      for (int n = 0; n < NB; n++) {
        acc[m][n] = __builtin_amdgcn_mfma_f32_16x16x32_bf16(a0, b[n][0], acc[m][n], 0, 0, 0);
        acc[m][n] = __builtin_amdgcn_mfma_f32_16x16x32_bf16(a1, b[n][1], acc[m][n], 0, 0, 0);
      }
    }
  }

#pragma unroll
  for (int m = 0; m < 8; m++)
#pragma unroll
    for (int n = 0; n < NB; n++)
#pragma unroll
      for (int r = 0; r < 4; r++) {
        long row = bm + wm2 * 128 + m * 16 + quad * 4 + r;
        long col = bn + wn4 * (NB * 16) + n * 16 + l16;
        if (OUT_BF16)
          ((ushort*)Cb)[row * ldC + col] = f2bf(acc[m][n][r]);
        else
          ((float*)Cb)[row * ldC + col] = acc[m][n][r];
      }
}

// ---------------- fused attention v6: zero-LDS, L2-direct operands ----------------
// pk+pvT total 4MB = fits every XCD L2 (per-chunk slices ~32KB ~ L1). Guide
// Common-mistake #7 / m169: staging L2-fit data in LDS is pure overhead. K-frags
// and V^T-frags are read straight from global at the SAME addresses v5 staged
// (bit-identical operand values, verified layout). No LDS, no barriers, no dbuf:
// occupancy is VGPR-limited (~12 waves/CU) and waves free-run over L2 latency.
// Softmax/P-path unchanged from v5 (swapped-QK 32x32, cvt_pk+permlane32_swap).
__global__ __launch_bounds__(256, 2) void attn_fused(
    const ushort* __restrict__ q_r,   // (B,H,S,HD), pre-scaled
    const ushort* __restrict__ pk,    // (B,KV,K,HD)
    const ushort* __restrict__ pvT,   // (B,KV,HD,K)
    ushort* __restrict__ attn) {      // (B,S,H*HD)
  const int bh = blockIdx.y;
  const int b = bh >> 4, h = bh & 15;
  const int kvh = h >> 2;
  const int wv = threadIdx.x >> 6, lane = threadIdx.x & 63;
  const int l31 = lane & 31, hi = lane >> 5;
  const int s0 = blockIdx.x * 128 + wv * 32;

  const ushort* pkb = pk + ((long)b * KV_ + kvh) * (K_ * HD_);
  const ushort* pvb = pvT + ((long)b * KV_ + kvh) * (HD_ * K_);

  // Q as B-operand frags: lane holds Q[s0+l31][s*16 + hi*8 .. +7]
  bf16x8 qb[8];
#pragma unroll
  for (int s = 0; s < 8; s++)
    qb[s] = *(const bf16x8*)(q_r + (((long)b * H_ + h) * S_ + s0 + l31) * HD_ + s * 16 + hi * 8);

  f32x16 O[4];
#pragma unroll
  for (int t = 0; t < 4; t++)
#pragma unroll
    for (int r = 0; r < 16; r++) O[t][r] = 0.f;
  float lsum = 0.f;  // partial row-sum for q = l31 (this lane's half of k)

  constexpr int NC = K_ / 64;

  for (int c = 0; c < NC; c++) {
    const int k0 = c * 64;

    // QK^T swapped: pacc[m] = K[k0+32m ..][:] x Q^T -> P[k][q], col q = l31
    f32x16 pacc0, pacc1;
#pragma unroll
    for (int r = 0; r < 16; r++) { pacc0[r] = 0.f; pacc1[r] = 0.f; }
    __builtin_amdgcn_s_setprio(1);
#pragma unroll
    for (int s = 0; s < 8; s++) {
      bf16x8 k0f = *(const bf16x8*)(pkb + (long)(k0 + l31) * HD_ + s * 16 + hi * 8);
      bf16x8 k1f = *(const bf16x8*)(pkb + (long)(k0 + 32 + l31) * HD_ + s * 16 + hi * 8);
      pacc0 = __builtin_amdgcn_mfma_f32_32x32x16_bf16(k0f, qb[s], pacc0, 0, 0, 0);
      pacc1 = __builtin_amdgcn_mfma_f32_32x32x16_bf16(k1f, qb[s], pacc1, 0, 0, 0);
    }
    __builtin_amdgcn_s_setprio(0);

    // softmax (no-max: exp(s-12)) fully in-register
#pragma unroll
    for (int r = 0; r < 16; r++) {
      pacc0[r] = __expf(pacc0[r] - 12.f);
      pacc1[r] = __expf(pacc1[r] - 12.f);
      lsum += pacc0[r] + pacc1[r];
    }

    // P -> A-frags: 16 cvt_pk + 8 permlane32_swap (s' = 2m+e)
    bf16x8 paf[4];
#pragma unroll
    for (int m = 0; m < 2; m++) {
#pragma unroll
      for (int e = 0; e < 2; e++) {
        float v0 = m ? pacc1[8 * e + 0] : pacc0[8 * e + 0];
        float v1 = m ? pacc1[8 * e + 1] : pacc0[8 * e + 1];
        float v2 = m ? pacc1[8 * e + 2] : pacc0[8 * e + 2];
        float v3 = m ? pacc1[8 * e + 3] : pacc0[8 * e + 3];
        float v4 = m ? pacc1[8 * e + 4] : pacc0[8 * e + 4];
        float v5 = m ? pacc1[8 * e + 5] : pacc0[8 * e + 5];
        float v6 = m ? pacc1[8 * e + 6] : pacc0[8 * e + 6];
        float v7 = m ? pacc1[8 * e + 7] : pacc0[8 * e + 7];
        unsigned int A0, A1, B0, B1;
        asm("v_cvt_pk_bf16_f32 %0, %1, %2" : "=v"(A0) : "v"(v0), "v"(v1));
        asm("v_cvt_pk_bf16_f32 %0, %1, %2" : "=v"(A1) : "v"(v2), "v"(v3));
        asm("v_cvt_pk_bf16_f32 %0, %1, %2" : "=v"(B0) : "v"(v4), "v"(v5));
        asm("v_cvt_pk_bf16_f32 %0, %1, %2" : "=v"(B1) : "v"(v6), "v"(v7));
        asm("v_permlane32_swap_b32 %0, %1" : "+v"(A0), "+v"(B0));
        asm("v_permlane32_swap_b32 %0, %1" : "+v"(A1), "+v"(B1));
        union { unsigned int u[4]; bf16x8 v; } w;
        w.u[0] = A0; w.u[1] = A1; w.u[2] = B0; w.u[3] = B1;
        paf[2 * m + e] = w.v;
      }
    }

    // PV: O[ht] += P(32q x 16k) x V^T-frag(16k x 32hd), V^T read L2-direct
    __builtin_amdgcn_s_setprio(1);
#pragma unroll
    for (int sp = 0; sp < 4; sp++) {
#pragma unroll
      for (int ht = 0; ht < 4; ht++) {
        int vr = ht * 32 + l31;
        bf16x8 vb = *(const bf16x8*)(pvb + (long)vr * K_ + k0 + sp * 16 + hi * 8);
        O[ht] = __builtin_amdgcn_mfma_f32_32x32x16_bf16(paf[sp], vb, O[ht], 0, 0, 0);
      }
    }
    __builtin_amdgcn_s_setprio(0);
  }

  // finalize: full row-sum for q=l31, then per-reg inverse via shfl
  lsum += __shfl_xor(lsum, 32);
  float inv_own = 1.f / lsum;
#pragma unroll
  for (int r = 0; r < 16; r++) {
    int q = (r & 3) + 8 * (r >> 2) + 4 * hi;
    float invq = __shfl(inv_own, q);
    long row = (long)b * S_ + s0 + q;
#pragma unroll
    for (int ht = 0; ht < 4; ht++)
      attn[row * (long)HID_ + h * HD_ + ht * 32 + l31] = f2bf(O[ht][r] * invq);
  }
}

// ---------------- host ----------------
extern "C" void kernel_launch(void* const* d_in, const int* in_sizes, int n_in,
                              void* d_out, int out_size, void* d_ws, size_t ws_size,
                              hipStream_t stream) {
  const float* hs = (const float*)d_in[0];
  const float* cosp = (const float*)d_in[1];
  const float* sinp = (const float*)d_in[2];
  // d_in[3] attention_mask: uniform over softmax axis -> provably a no-op
  const float* Wq = (const float*)d_in[4];
  const float* bq = (const float*)d_in[5];
  const float* Wk = (const float*)d_in[6];
  const float* bk = (const float*)d_in[7];
  const float* Wv = (const float*)d_in[8];
  const float* bv = (const float*)d_in[9];
  const float* Wo = (const float*)d_in[10];
  const float* E = (const float*)d_in[11];
  const float* Fp = (const float*)d_in[12];
  float* out = (float*)d_out;

  ushort* w = (ushort*)d_ws;
  ushort* hs_bf = w;            w += 16777216;  // (8192,2048); later: fp32 pkpv partials
  ushort* WqkvT = w;            w += 6291456;   // (3072,2048)
  ushort* WoT = w;              w += 4194304;   // (2048,2048)
  ushort* E_T = w;              w += 4194304;   // (1024,4096)
  ushort* Fp_T = w;             w += 4194304;   // (1024,4096)
  ushort* Cqkv = w;             w += 25165824;  // (8192,3072)
  ushort* q_r = w;              w += 16777216;  // (B,H,S,HD)
  ushort* k_r = w;              w += 4194304;   // (B,KV,S,HD)
  ushort* v_r = w;              w += 4194304;
  ushort* k_rT = w;             w += 4194304;   // (B,KV,HD,S)
  ushort* v_rT = w;             w += 4194304;
  ushort* pk = w;               w += 1048576;   // (B,KV,K,HD)  — contiguous with pvT!
  ushort* pvT = w;              w += 1048576;   // (B,KV,HD,K)
  ushort* attnb = Cqkv;  // alias: Cqkv dead after rope_qkv

  dim3 tb(32, 8);
  cast_f32_bf16<<<16384, 256, 0, stream>>>(hs, hs_bf, 16777216L);
  transpose_all<<<18432, tb, 0, stream>>>(Wq, Wk, Wv, Wo, E, Fp, WqkvT, WoT, E_T, Fp_T);

  // fused QKV projection: (8192,2048) @ (3072,2048)^T -> (8192,3072)
  // 256x192 8-phase: 32*16 = 512 blocks = exactly 2 full rounds at 1 block/CU
  gemm8_nt<3, true><<<dim3(512), 512, 0, stream>>>(hs_bf, WqkvT, Cqkv, 16, 32, 2048, 2048, 3072);

  rope_qkv<<<dim3(24, 128, 2), 256, 0, stream>>>(Cqkv, bq, bk, bv, cosp, sinp, q_r, k_r, v_r);

  transpose_bf16<<<dim3(4, 128, 8), tb, 0, stream>>>(k_r, k_rT, 4096, 128, 524288, 524288);
  transpose_bf16<<<dim3(4, 128, 8), tb, 0, stream>>>(v_r, v_rT, 4096, 128, 524288, 524288);

  // pk + pvT: split-K x4 into fp32 partials (reusing dead hs_bf region), then reduce
  float* part = (float*)hs_bf;  // 4 x 2097152 floats = 33.55 MB (fits exactly)
  gemm_pkpv<<<dim3(8, 16, 4), 256, 0, stream>>>(E_T, k_rT, v_rT, Fp_T, part);
  reduce4_bf16<<<2048, 256, 0, stream>>>(part, pk);

  attn_fused<<<dim3(32, 32), 256, 0, stream>>>(q_r, pk, pvT, attnb);

  // output projection -> fp32 out, 8-phase 256^2 (256 blocks = exactly 1 round)
  gemm8_nt<4, false><<<dim3(256), 512, 0, stream>>>(attnb, WoT, out, 8, 32, 2048, 2048, 2048);
}

// Round 9
// 513.377 us; speedup vs baseline: 1.3437x; 1.3437x over previous
//
#include <hip/hip_runtime.h>
#include <math.h>

#define B_ 2
#define S_ 4096
#define HID_ 2048
#define H_ 16
#define KV_ 4
#define HD_ 128
#define K_ 1024
#define GROUPS_ 4
#define SCALE_ 0.08838834764831845f

typedef __bf16 bf16x8 __attribute__((ext_vector_type(8)));
typedef float f32x4 __attribute__((ext_vector_type(4)));
typedef float f32x8 __attribute__((ext_vector_type(8)));
typedef float f32x16 __attribute__((ext_vector_type(16)));
typedef ushort u16x8 __attribute__((ext_vector_type(8)));

__device__ __forceinline__ ushort f2bf(float f) {
  union { float f; unsigned int u; } x; x.f = f;
  unsigned int u = x.u;
  u += 0x7FFFu + ((u >> 16) & 1u);
  return (ushort)(u >> 16);
}
__device__ __forceinline__ float bf2f(ushort s) {
  union { unsigned int u; float f; } x; x.u = ((unsigned int)s) << 16;
  return x.f;
}

// async global->LDS, 16B per lane; LDS dest = uniform base + lane*16 [m97/m104]
__device__ __forceinline__ void gld16(const ushort* g, ushort* l) {
  __builtin_amdgcn_global_load_lds((const __attribute__((address_space(1))) void*)g,
                                   (__attribute__((address_space(3))) void*)l, 16, 0, 0);
}

// ---------------- elementwise cast fp32 -> bf16 ----------------
__global__ void cast_f32_bf16(const float* __restrict__ in, ushort* __restrict__ out, long n) {
  long i = ((long)blockIdx.x * blockDim.x + threadIdx.x) * 4;
  if (i >= n) return;
  float4 v = *(const float4*)(in + i);
  ushort4 o;
  o.x = f2bf(v.x); o.y = f2bf(v.y); o.z = f2bf(v.z); o.w = f2bf(v.w);
  *(ushort4*)(out + i) = o;
}

// ---------------- ALL fp32->bf16 weight transposes in ONE launch ----------------
__global__ void transpose_all(const float* __restrict__ Wq, const float* __restrict__ Wk,
                              const float* __restrict__ Wv, const float* __restrict__ Wo,
                              const float* __restrict__ E, const float* __restrict__ Fp,
                              ushort* __restrict__ WqkvT, ushort* __restrict__ WoT,
                              ushort* __restrict__ E_T, ushort* __restrict__ Fp_T) {
  __shared__ float t[32][33];
  int id = blockIdx.x;
  const float* src; ushort* dst; int R, C;
  if (id < 4096)       { src = Wq; dst = WqkvT;           R = 2048; C = 2048; }
  else if (id < 5120)  { src = Wk; dst = WqkvT + 4194304; R = 2048; C = 512;  id -= 4096; }
  else if (id < 6144)  { src = Wv; dst = WqkvT + 5242880; R = 2048; C = 512;  id -= 5120; }
  else if (id < 10240) { src = Wo; dst = WoT;             R = 2048; C = 2048; id -= 6144; }
  else if (id < 14336) { src = E;  dst = E_T;             R = 4096; C = 1024; id -= 10240; }
  else                 { src = Fp; dst = Fp_T;            R = 4096; C = 1024; id -= 14336; }
  int tX = C >> 5;
  int c0 = (id % tX) * 32, r0 = (id / tX) * 32;
  int tx = threadIdx.x, ty = threadIdx.y;
#pragma unroll
  for (int i = 0; i < 4; i++)
    t[ty + i * 8][tx] = src[(long)(r0 + ty + i * 8) * C + c0 + tx];
  __syncthreads();
#pragma unroll
  for (int i = 0; i < 4; i++)
    dst[(long)(c0 + ty + i * 8) * R + r0 + tx] = f2bf(t[tx][ty + i * 8]);
}

// ---------------- tiled transpose bf16, batched ----------------
__global__ void transpose_bf16(const ushort* __restrict__ in, ushort* __restrict__ out,
                               int R, int C, long sIn, long sOut) {
  __shared__ ushort t[32][34];
  in += (long)blockIdx.z * sIn;
  out += (long)blockIdx.z * sOut;
  int c0 = blockIdx.x * 32, r0 = blockIdx.y * 32;
  int tx = threadIdx.x, ty = threadIdx.y;
#pragma unroll
  for (int i = 0; i < 4; i++)
    t[ty + i * 8][tx] = in[(long)(r0 + ty + i * 8) * C + c0 + tx];
  __syncthreads();
#pragma unroll
  for (int i = 0; i < 4; i++)
    out[(long)(c0 + ty + i * 8) * R + r0 + tx] = t[tx][ty + i * 8];
}

// ---------------- RoPE + bias + layout, vectorized (short8/float8 per lane) ----------
// grid (24 heads, S/32, B); 8 lanes per row, each handles d = dt..dt+7 and d+64.
__global__ __launch_bounds__(256) void rope_qkv(
    const ushort* __restrict__ Cqkv,
    const float* __restrict__ bq, const float* __restrict__ bk,
    const float* __restrict__ bv,
    const float* __restrict__ cosp, const float* __restrict__ sinp,
    ushort* __restrict__ q_r, ushort* __restrict__ k_r, ushort* __restrict__ v_r) {
  int head = blockIdx.x;  // 0..23: 16 q heads, 4 k, 4 v
  int s = blockIdx.y * 32 + (threadIdx.x >> 3);
  int b = blockIdx.z;
  int dt = (threadIdx.x & 7) * 8;
  long cs = ((long)b * S_ + s) * HD_;
  f32x8 c1 = *(const f32x8*)(cosp + cs + dt);
  f32x8 c2 = *(const f32x8*)(cosp + cs + dt + 64);
  f32x8 s1 = *(const f32x8*)(sinp + cs + dt);
  f32x8 s2 = *(const f32x8*)(sinp + cs + dt + 64);
  long rowbase = ((long)b * S_ + s) * 3072;
  if (head < H_) {
    int h = head;
    long in = rowbase + h * HD_ + dt;
    u16x8 x1v = *(const u16x8*)(Cqkv + in);
    u16x8 x2v = *(const u16x8*)(Cqkv + in + 64);
    f32x8 b1 = *(const f32x8*)(bq + h * HD_ + dt);
    f32x8 b2 = *(const f32x8*)(bq + h * HD_ + dt + 64);
    u16x8 o1v, o2v;
#pragma unroll
    for (int j = 0; j < 8; j++) {
      float x1 = bf2f(x1v[j]) + b1[j];
      float x2 = bf2f(x2v[j]) + b2[j];
      o1v[j] = f2bf((x1 * c1[j] - x2 * s1[j]) * SCALE_);
      o2v[j] = f2bf((x2 * c2[j] + x1 * s2[j]) * SCALE_);
    }
    long ob = (((long)b * H_ + h) * S_ + s) * HD_ + dt;
    *(u16x8*)(q_r + ob) = o1v;
    *(u16x8*)(q_r + ob + 64) = o2v;
  } else if (head < H_ + KV_) {
    int kv = head - H_;
    long in = rowbase + 2048 + kv * HD_ + dt;
    u16x8 x1v = *(const u16x8*)(Cqkv + in);
    u16x8 x2v = *(const u16x8*)(Cqkv + in + 64);
    f32x8 b1 = *(const f32x8*)(bk + kv * HD_ + dt);
    f32x8 b2 = *(const f32x8*)(bk + kv * HD_ + dt + 64);
    u16x8 o1v, o2v;
#pragma unroll
    for (int j = 0; j < 8; j++) {
      float x1 = bf2f(x1v[j]) + b1[j];
      float x2 = bf2f(x2v[j]) + b2[j];
      o1v[j] = f2bf(x1 * c1[j] - x2 * s1[j]);
      o2v[j] = f2bf(x2 * c2[j] + x1 * s2[j]);
    }
    long ob = (((long)b * KV_ + kv) * S_ + s) * HD_ + dt;
    *(u16x8*)(k_r + ob) = o1v;
    *(u16x8*)(k_r + ob + 64) = o2v;
  } else {
    int kv = head - H_ - KV_;
    long in = rowbase + 2560 + kv * HD_ + dt;
    u16x8 x1v = *(const u16x8*)(Cqkv + in);
    u16x8 x2v = *(const u16x8*)(Cqkv + in + 64);
    f32x8 b1 = *(const f32x8*)(bv + kv * HD_ + dt);
    f32x8 b2 = *(const f32x8*)(bv + kv * HD_ + dt + 64);
    u16x8 o1v, o2v;
#pragma unroll
    for (int j = 0; j < 8; j++) {
      o1v[j] = f2bf(bf2f(x1v[j]) + b1[j]);
      o2v[j] = f2bf(bf2f(x2v[j]) + b2[j]);
    }
    long ob = (((long)b * KV_ + kv) * S_ + s) * HD_ + dt;
    *(u16x8*)(v_r + ob) = o1v;
    *(u16x8*)(v_r + ob + 64) = o2v;
  }
}

// ---------------- NT GEMM body (m97 structure + XOR swizzle) — kept for pkpv ----------------
template <int BM, int BN, bool OUT_BF16>
__device__ __forceinline__ void gemm_body(
    const ushort* __restrict__ Ab, const ushort* __restrict__ Bb, void* __restrict__ Cb,
    int bm, int bn, int k0, int k1, int ldA, int ldB, int ldC, float scale) {
  __shared__ alignas(16) ushort As[BM * 32];
  __shared__ alignas(16) ushort Bs[BN * 32];
  constexpr int MT = BM / 32, NT = BN / 32;
  const int tid = threadIdx.x;
  const int wv = tid >> 6, lane = tid & 63;
  const int quad = lane >> 4, l16 = lane & 15;
  const int wm = (wv >> 1) * (BM / 2);
  const int wn = (wv & 1) * (BN / 2);
  const int srow = lane >> 2;
  const int scp = lane & 3;
  f32x4 acc[MT][NT];
#pragma unroll
  for (int i = 0; i < MT; i++)
#pragma unroll
    for (int j = 0; j < NT; j++)
#pragma unroll
      for (int r = 0; r < 4; r++) acc[i][j][r] = 0.f;
  const int sw = quad ^ ((l16 >> 1) & 3);
  for (int kk = k0; kk < k1; kk += 32) {
    __syncthreads();
#pragma unroll
    for (int j = 0; j < BM / 64; j++) {
      int r0 = wv * (BM / 4) + j * 16;
      int row = r0 + srow;
      gld16(Ab + (long)(bm + row) * ldA + kk + (scp ^ ((row >> 1) & 3)) * 8, &As[r0 * 32]);
    }
#pragma unroll
    for (int j = 0; j < BN / 64; j++) {
      int r0 = wv * (BN / 4) + j * 16;
      int row = r0 + srow;
      gld16(Bb + (long)(bn + row) * ldB + kk + (scp ^ ((row >> 1) & 3)) * 8, &Bs[r0 * 32]);
    }
    __syncthreads();
    bf16x8 af[MT], bf[NT];
#pragma unroll
    for (int i = 0; i < MT; i++)
      af[i] = *(const bf16x8*)&As[(wm + i * 16 + l16) * 32 + sw * 8];
#pragma unroll
    for (int j = 0; j < NT; j++)
      bf[j] = *(const bf16x8*)&Bs[(wn + j * 16 + l16) * 32 + sw * 8];
#pragma unroll
    for (int i = 0; i < MT; i++)
#pragma unroll
      for (int j = 0; j < NT; j++)
        acc[i][j] = __builtin_amdgcn_mfma_f32_16x16x32_bf16(af[i], bf[j], acc[i][j], 0, 0, 0);
  }
#pragma unroll
  for (int i = 0; i < MT; i++)
#pragma unroll
    for (int j = 0; j < NT; j++)
#pragma unroll
      for (int r = 0; r < 4; r++) {
        long row = bm + wm + i * 16 + quad * 4 + r;
        long col = bn + wn + j * 16 + l16;
        float v = acc[i][j][r] * scale;
        if (OUT_BF16)
          ((ushort*)Cb)[row * ldC + col] = f2bf(v);
        else
          ((float*)Cb)[row * ldC + col] = v;
      }
}

// pk/pvT with split-K x4: fp32 partials. grid (8 tiles, 16 z, 4 kseg)
__global__ __launch_bounds__(256) void gemm_pkpv(
    const ushort* __restrict__ E_T, const ushort* __restrict__ k_rT,
    const ushort* __restrict__ v_rT, const ushort* __restrict__ Fp_T,
    float* __restrict__ part) {
  int z = blockIdx.y, ks = blockIdx.z;
  const ushort *A, *Bt;
  int bm, bn, ldC;
  if (z < 8) {  // pk[z] (K_,HD) = E_T @ k_rT[z]^T
    A = E_T; Bt = k_rT + (long)z * 524288;
    bm = blockIdx.x * 128; bn = 0; ldC = 128;
  } else {      // pvT[z-8] (HD,K_) = v_rT @ Fp_T^T
    A = v_rT + (long)(z - 8) * 524288; Bt = Fp_T;
    bm = 0; bn = blockIdx.x * 128; ldC = 1024;
  }
  float* Cb = part + (long)ks * 2097152 + (long)z * 131072;
  gemm_body<128, 128, false>(A, Bt, Cb, bm, bn, ks * 1024, ks * 1024 + 1024,
                             4096, 4096, ldC, 1.f);
}

// sum 4 fp32 partial slabs -> bf16 (pk||pvT contiguous)
__global__ void reduce4_bf16(const float* __restrict__ part, ushort* __restrict__ out) {
  long i = ((long)blockIdx.x * 256 + threadIdx.x) * 4;
  float4 a = *(const float4*)(part + i);
  float4 b = *(const float4*)(part + 2097152 + i);
  float4 c = *(const float4*)(part + 4194304 + i);
  float4 d = *(const float4*)(part + 6291456 + i);
  ushort4 o;
  o.x = f2bf(a.x + b.x + c.x + d.x);
  o.y = f2bf(a.y + b.y + c.y + d.y);
  o.z = f2bf(a.z + b.z + c.z + d.z);
  o.w = f2bf(a.w + b.w + c.w + d.w);
  *(ushort4*)(out + i) = o;
}

// ---------------- 256 x (NB*64) 8-phase NT GEMM (T2+T3+T4+T5), relaxed publish ----------
template <int NB, bool OUT_BF16>
__global__ __launch_bounds__(512, 2) void gemm8_nt(
    const ushort* __restrict__ Ab, const ushort* __restrict__ Bb, void* __restrict__ Cb,
    int ntn, int NT, int ldA, int ldB, int ldC) {
  __shared__ alignas(16) ushort As[2][256 * 64];        // 64 KB
  __shared__ alignas(16) ushort Bs[2][NB * 64 * 64];    // NB*16 KB
  const int nwg = gridDim.x;
  const int cpx = nwg >> 3;  // blocks per XCD (grids are %8==0)
  const int bid = blockIdx.x;
  const int swz = (bid & 7) * cpx + (bid >> 3);  // XCD-contiguous chunks (T1, bijective)
  const int bm = (swz / ntn) * 256, bn = (swz % ntn) * (NB * 64);
  const int tid = threadIdx.x;
  const int wv = tid >> 6, lane = tid & 63;
  const int quad = lane >> 4, l16 = lane & 15, l7 = l16 & 7;
  const int wm2 = wv >> 2, wn4 = wv & 3;
  const int ida = wn4;
  const int ha = wm2;
  const int lrow = lane >> 3, lchk = lane & 7;
  const int schk = (lchk ^ lrow) * 8;  // pre-swizzled source chunk (rule 21)

  auto stageBown = [&](int buf, int kt) {
#pragma unroll
    for (int j = 0; j < NB; j++) {
      int rloc = wn4 * (NB * 16) + j * 16 + wm2 * 8;
      int r = rloc + lrow;
      gld16(Bb + (long)(bn + r) * ldB + kt * 64 + schk, &Bs[buf][rloc * 64]);
    }
  };
  auto stageA = [&](int buf, int kt, int sp) {
#pragma unroll
    for (int j = 0; j < 2; j++) {
      int rloc = ha * 128 + sp * 64 + j * 32 + ida * 8;
      int r = rloc + lrow;
      gld16(Ab + (long)(bm + r) * ldA + kt * 64 + schk, &As[buf][rloc * 64]);
    }
  };
  auto rdA = [&](int buf, int m, int ks) -> bf16x8 {
    int ra = wm2 * 128 + m * 16 + l16;
    int c = (ks * 4 + quad) ^ l7;
    return *(const bf16x8*)&As[buf][ra * 64 + c * 8];
  };
  auto rdB = [&](int buf, int n, int ks) -> bf16x8 {
    int rb = wn4 * (NB * 16) + n * 16 + l16;
    int c = (ks * 4 + quad) ^ l7;
    return *(const bf16x8*)&Bs[buf][rb * 64 + c * 8];
  };

  f32x4 acc[8][NB];
#pragma unroll
  for (int m = 0; m < 8; m++)
#pragma unroll
    for (int n = 0; n < NB; n++)
#pragma unroll
      for (int r = 0; r < 4; r++) acc[m][n][r] = 0.f;

  stageBown(0, 0); stageA(0, 0, 0); stageA(0, 0, 1);
  asm volatile("s_waitcnt vmcnt(2)" ::: "memory");
  __builtin_amdgcn_s_barrier();

#pragma unroll 2
  for (int t = 0; t < NT - 1; ++t) {
    const int cur = t & 1, nxt = cur ^ 1;
    const int kt1 = t + 1;
    bf16x8 b[NB][2], x0[2], x1[2];
#pragma unroll
    for (int n = 0; n < NB; n++) { b[n][0] = rdB(cur, n, 0); b[n][1] = rdB(cur, n, 1); }
    x0[0] = rdA(cur, 0, 0); x0[1] = rdA(cur, 0, 1);
    x1[0] = rdA(cur, 1, 0); x1[1] = rdA(cur, 1, 1);
    stageBown(nxt, kt1);
    __builtin_amdgcn_s_barrier();
    asm volatile("s_waitcnt lgkmcnt(0)" ::: "memory");
    __builtin_amdgcn_s_setprio(1);
#pragma unroll
    for (int n = 0; n < NB; n++)
#pragma unroll
      for (int ks = 0; ks < 2; ks++) {
        acc[0][n] = __builtin_amdgcn_mfma_f32_16x16x32_bf16(x0[ks], b[n][ks], acc[0][n], 0, 0, 0);
        acc[1][n] = __builtin_amdgcn_mfma_f32_16x16x32_bf16(x1[ks], b[n][ks], acc[1][n], 0, 0, 0);
      }
    __builtin_amdgcn_s_setprio(0);
    __builtin_amdgcn_s_barrier();
    x0[0] = rdA(cur, 2, 0); x0[1] = rdA(cur, 2, 1);
    x1[0] = rdA(cur, 3, 0); x1[1] = rdA(cur, 3, 1);
    stageA(nxt, kt1, 0);
    if constexpr (NB == 3) asm volatile("s_waitcnt vmcnt(5)" ::: "memory");
    else                   asm volatile("s_waitcnt vmcnt(6)" ::: "memory");
    __builtin_amdgcn_s_barrier();
    asm volatile("s_waitcnt lgkmcnt(0)" ::: "memory");
    __builtin_amdgcn_s_setprio(1);
#pragma unroll
    for (int n = 0; n < NB; n++)
#pragma unroll
      for (int ks = 0; ks < 2; ks++) {
        acc[2][n] = __builtin_amdgcn_mfma_f32_16x16x32_bf16(x0[ks], b[n][ks], acc[2][n], 0, 0, 0);
        acc[3][n] = __builtin_amdgcn_mfma_f32_16x16x32_bf16(x1[ks], b[n][ks], acc[3][n], 0, 0, 0);
      }
    __builtin_amdgcn_s_setprio(0);
    __builtin_amdgcn_s_barrier();
    x0[0] = rdA(cur, 4, 0); x0[1] = rdA(cur, 4, 1);
    x1[0] = rdA(cur, 5, 0); x1[1] = rdA(cur, 5, 1);
    stageA(nxt, kt1, 1);
    __builtin_amdgcn_s_barrier();
    asm volatile("s_waitcnt lgkmcnt(0)" ::: "memory");
    __builtin_amdgcn_s_setprio(1);
#pragma unroll
    for (int n = 0; n < NB; n++)
#pragma unroll
      for (int ks = 0; ks < 2; ks++) {
        acc[4][n] = __builtin_amdgcn_mfma_f32_16x16x32_bf16(x0[ks], b[n][ks], acc[4][n], 0, 0, 0);
        acc[5][n] = __builtin_amdgcn_mfma_f32_16x16x32_bf16(x1[ks], b[n][ks], acc[5][n], 0, 0, 0);
      }
    __builtin_amdgcn_s_setprio(0);
    __builtin_amdgcn_s_barrier();
    x0[0] = rdA(cur, 6, 0); x0[1] = rdA(cur, 6, 1);
    x1[0] = rdA(cur, 7, 0); x1[1] = rdA(cur, 7, 1);
    asm volatile("s_waitcnt vmcnt(2)" ::: "memory");
    __builtin_amdgcn_s_barrier();
    asm volatile("s_waitcnt lgkmcnt(0)" ::: "memory");
    __builtin_amdgcn_s_setprio(1);
#pragma unroll
    for (int n = 0; n < NB; n++)
#pragma unroll
      for (int ks = 0; ks < 2; ks++) {
        acc[6][n] = __builtin_amdgcn_mfma_f32_16x16x32_bf16(x0[ks], b[n][ks], acc[6][n], 0, 0, 0);
        acc[7][n] = __builtin_amdgcn_mfma_f32_16x16x32_bf16(x1[ks], b[n][ks], acc[7][n], 0, 0, 0);
      }
    __builtin_amdgcn_s_setprio(0);
    __builtin_amdgcn_s_barrier();
  }

  {
    const int cur = (NT - 1) & 1;
    asm volatile("s_waitcnt vmcnt(0)" ::: "memory");
    __builtin_amdgcn_s_barrier();
    bf16x8 b[NB][2];
#pragma unroll
    for (int n = 0; n < NB; n++) { b[n][0] = rdB(cur, n, 0); b[n][1] = rdB(cur, n, 1); }
#pragma unroll
    for (int m = 0; m < 8; m++) {
      bf16x8 a0 = rdA(cur, m, 0), a1 = rdA(cur, m, 1);
#pragma unroll
      for (int n = 0; n < NB; n++) {
        acc[m][n] = __builtin_amdgcn_mfma_f32_16x16x32_bf16(a0, b[n][0], acc[m][n], 0, 0, 0);
        acc[m][n] = __builtin_amdgcn_mfma_f32_16x16x32_bf16(a1, b[n][1], acc[m][n], 0, 0, 0);
      }
    }
  }

#pragma unroll
  for (int m = 0; m < 8; m++)
#pragma unroll
    for (int n = 0; n < NB; n++)
#pragma unroll
      for (int r = 0; r < 4; r++) {
        long row = bm + wm2 * 128 + m * 16 + quad * 4 + r;
        long col = bn + wn4 * (NB * 16) + n * 16 + l16;
        if (OUT_BF16)
          ((ushort*)Cb)[row * ldC + col] = f2bf(acc[m][n][r]);
        else
          ((float*)Cb)[row * ldC + col] = acc[m][n][r];
      }
}

// ---------------- fused attention v5 (reverted from v6): swapped-QK 32x32, LDS-staged ----
// v6 post-mortem: L2-direct operand loads serialized (no prefetch structure, VGPR-
// limited outstanding loads) -> 2.7x regression. gld16 staging IS the prefetch:
// fire-and-forget, latency amortized behind one barrier per chunk. Keep v5.
__device__ __forceinline__ void stage_chunk(const ushort* __restrict__ pkb,
                                            const ushort* __restrict__ pvb,
                                            ushort* __restrict__ bk, ushort* __restrict__ bv,
                                            int k0, int wv, int lane) {
  const int sr4 = lane >> 4, cp16 = lane & 15;  // pk staging: 4 rows x 16 chunks
  const int sr8 = lane >> 3, cp8 = lane & 7;    // pv staging: 8 rows x 8 chunks
#pragma unroll
  for (int j = 0; j < 4; j++) {  // pk rows k0 + wv*16+j*4 .. +3
    int kr = wv * 16 + j * 4 + sr4;
    gld16(pkb + (long)(k0 + kr) * HD_ + (cp16 ^ (kr & 7)) * 8, bk + (wv * 16 + j * 4) * HD_);
  }
#pragma unroll
  for (int j = 0; j < 4; j++) {  // pv rows (hd) wv*32+j*8 .. +7
    int hd = wv * 32 + j * 8 + sr8;
    gld16(pvb + (long)hd * K_ + k0 + (cp8 ^ (hd & 7)) * 8, bv + (wv * 32 + j * 8) * 64);
  }
}

__global__ __launch_bounds__(256, 2) void attn_fused(
    const ushort* __restrict__ q_r,   // (B,H,S,HD), pre-scaled
    const ushort* __restrict__ pk,    // (B,KV,K,HD)
    const ushort* __restrict__ pvT,   // (B,KV,HD,K)
    ushort* __restrict__ attn) {      // (B,S,H*HD)
  __shared__ alignas(16) ushort Bk[2][64 * HD_];   // 32 KB (double-buffered)
  __shared__ alignas(16) ushort Bv[2][HD_ * 64];   // 32 KB (double-buffered)
  const int bh = blockIdx.y;
  const int b = bh >> 4, h = bh & 15;
  const int kvh = h >> 2;
  const int wv = threadIdx.x >> 6, lane = threadIdx.x & 63;
  const int l31 = lane & 31, hi = lane >> 5, k7 = l31 & 7;
  const int s0 = blockIdx.x * 128 + wv * 32;

  const ushort* pkb = pk + ((long)b * KV_ + kvh) * (K_ * HD_);
  const ushort* pvb = pvT + ((long)b * KV_ + kvh) * (HD_ * K_);

  // Q as B-operand frags: lane holds Q[s0+l31][s*16 + hi*8 .. +7]
  bf16x8 qb[8];
#pragma unroll
  for (int s = 0; s < 8; s++)
    qb[s] = *(const bf16x8*)(q_r + (((long)b * H_ + h) * S_ + s0 + l31) * HD_ + s * 16 + hi * 8);

  f32x16 O[4];
#pragma unroll
  for (int t = 0; t < 4; t++)
#pragma unroll
    for (int r = 0; r < 16; r++) O[t][r] = 0.f;
  float lsum = 0.f;  // partial row-sum for q = l31 (this lane's half of k)

  constexpr int NC = K_ / 64;

  // prologue: stage chunk 0; __syncthreads drains vmcnt -> visible
  stage_chunk(pkb, pvb, &Bk[0][0], &Bv[0][0], 0, wv, lane);
  __syncthreads();

  for (int c = 0; c < NC; c++) {
    const int cur = c & 1;
    if (c + 1 < NC)
      stage_chunk(pkb, pvb, &Bk[cur ^ 1][0], &Bv[cur ^ 1][0], (c + 1) * 64, wv, lane);

    const ushort* bkc = &Bk[cur][0];
    const ushort* bvc = &Bv[cur][0];

    // QK^T swapped: pacc[m] = K[32m..32m+31][:] x Q^T -> P[k][q], col q = l31
    f32x16 pacc0, pacc1;
#pragma unroll
    for (int r = 0; r < 16; r++) { pacc0[r] = 0.f; pacc1[r] = 0.f; }
    __builtin_amdgcn_s_setprio(1);
#pragma unroll
    for (int s = 0; s < 8; s++) {
      int cc = ((2 * s + hi) ^ k7) * 8;
      bf16x8 k0 = *(const bf16x8*)&bkc[l31 * HD_ + cc];
      bf16x8 k1 = *(const bf16x8*)&bkc[(32 + l31) * HD_ + cc];
      pacc0 = __builtin_amdgcn_mfma_f32_32x32x16_bf16(k0, qb[s], pacc0, 0, 0, 0);
      pacc1 = __builtin_amdgcn_mfma_f32_32x32x16_bf16(k1, qb[s], pacc1, 0, 0, 0);
    }
    __builtin_amdgcn_s_setprio(0);

    // softmax (no-max: exp(s-12)) fully in-register
#pragma unroll
    for (int r = 0; r < 16; r++) {
      pacc0[r] = __expf(pacc0[r] - 12.f);
      pacc1[r] = __expf(pacc1[r] - 12.f);
      lsum += pacc0[r] + pacc1[r];
    }

    // P -> A-frags: 16 cvt_pk + 8 permlane32_swap (s' = 2m+e)
    bf16x8 paf[4];
#pragma unroll
    for (int m = 0; m < 2; m++) {
#pragma unroll
      for (int e = 0; e < 2; e++) {
        float v0 = m ? pacc1[8 * e + 0] : pacc0[8 * e + 0];
        float v1 = m ? pacc1[8 * e + 1] : pacc0[8 * e + 1];
        float v2 = m ? pacc1[8 * e + 2] : pacc0[8 * e + 2];
        float v3 = m ? pacc1[8 * e + 3] : pacc0[8 * e + 3];
        float v4 = m ? pacc1[8 * e + 4] : pacc0[8 * e + 4];
        float v5 = m ? pacc1[8 * e + 5] : pacc0[8 * e + 5];
        float v6 = m ? pacc1[8 * e + 6] : pacc0[8 * e + 6];
        float v7 = m ? pacc1[8 * e + 7] : pacc0[8 * e + 7];
        unsigned int A0, A1, B0, B1;
        asm("v_cvt_pk_bf16_f32 %0, %1, %2" : "=v"(A0) : "v"(v0), "v"(v1));
        asm("v_cvt_pk_bf16_f32 %0, %1, %2" : "=v"(A1) : "v"(v2), "v"(v3));
        asm("v_cvt_pk_bf16_f32 %0, %1, %2" : "=v"(B0) : "v"(v4), "v"(v5));
        asm("v_cvt_pk_bf16_f32 %0, %1, %2" : "=v"(B1) : "v"(v6), "v"(v7));
        asm("v_permlane32_swap_b32 %0, %1" : "+v"(A0), "+v"(B0));
        asm("v_permlane32_swap_b32 %0, %1" : "+v"(A1), "+v"(B1));
        union { unsigned int u[4]; bf16x8 v; } w;
        w.u[0] = A0; w.u[1] = A1; w.u[2] = B0; w.u[3] = B1;
        paf[2 * m + e] = w.v;
      }
    }

    // PV: O[ht] += P(32q x 16k) x V^T-frag(16k x 32hd)
    __builtin_amdgcn_s_setprio(1);
#pragma unroll
    for (int sp = 0; sp < 4; sp++) {
#pragma unroll
      for (int ht = 0; ht < 4; ht++) {
        int vr = ht * 32 + l31;
        bf16x8 vb = *(const bf16x8*)&bvc[vr * 64 + (((2 * sp + hi) ^ (vr & 7)) * 8)];
        O[ht] = __builtin_amdgcn_mfma_f32_32x32x16_bf16(paf[sp], vb, O[ht], 0, 0, 0);
      }
    }
    __builtin_amdgcn_s_setprio(0);

    __syncthreads();
  }

  // finalize: full row-sum for q=l31, then per-reg inverse via shfl
  lsum += __shfl_xor(lsum, 32);
  float inv_own = 1.f / lsum;
#pragma unroll
  for (int r = 0; r < 16; r++) {
    int q = (r & 3) + 8 * (r >> 2) + 4 * hi;
    float invq = __shfl(inv_own, q);
    long row = (long)b * S_ + s0 + q;
#pragma unroll
    for (int ht = 0; ht < 4; ht++)
      attn[row * (long)HID_ + h * HD_ + ht * 32 + l31] = f2bf(O[ht][r] * invq);
  }
}

// ---------------- host ----------------
extern "C" void kernel_launch(void* const* d_in, const int* in_sizes, int n_in,
                              void* d_out, int out_size, void* d_ws, size_t ws_size,
                              hipStream_t stream) {
  const float* hs = (const float*)d_in[0];
  const float* cosp = (const float*)d_in[1];
  const float* sinp = (const float*)d_in[2];
  // d_in[3] attention_mask: uniform over softmax axis -> provably a no-op
  const float* Wq = (const float*)d_in[4];
  const float* bq = (const float*)d_in[5];
  const float* Wk = (const float*)d_in[6];
  const float* bk = (const float*)d_in[7];
  const float* Wv = (const float*)d_in[8];
  const float* bv = (const float*)d_in[9];
  const float* Wo = (const float*)d_in[10];
  const float* E = (const float*)d_in[11];
  const float* Fp = (const float*)d_in[12];
  float* out = (float*)d_out;

  ushort* w = (ushort*)d_ws;
  ushort* hs_bf = w;            w += 16777216;  // (8192,2048); later: fp32 pkpv partials
  ushort* WqkvT = w;            w += 6291456;   // (3072,2048)
  ushort* WoT = w;              w += 4194304;   // (2048,2048)
  ushort* E_T = w;              w += 4194304;   // (1024,4096)
  ushort* Fp_T = w;             w += 4194304;   // (1024,4096)
  ushort* Cqkv = w;             w += 25165824;  // (8192,3072)
  ushort* q_r = w;              w += 16777216;  // (B,H,S,HD)
  ushort* k_r = w;              w += 4194304;   // (B,KV,S,HD)
  ushort* v_r = w;              w += 4194304;
  ushort* k_rT = w;             w += 4194304;   // (B,KV,HD,S)
  ushort* v_rT = w;             w += 4194304;
  ushort* pk = w;               w += 1048576;   // (B,KV,K,HD)  — contiguous with pvT!
  ushort* pvT = w;              w += 1048576;   // (B,KV,HD,K)
  ushort* attnb = Cqkv;  // alias: Cqkv dead after rope_qkv

  dim3 tb(32, 8);
  cast_f32_bf16<<<16384, 256, 0, stream>>>(hs, hs_bf, 16777216L);
  transpose_all<<<18432, tb, 0, stream>>>(Wq, Wk, Wv, Wo, E, Fp, WqkvT, WoT, E_T, Fp_T);

  // fused QKV projection: (8192,2048) @ (3072,2048)^T -> (8192,3072)
  // 256x192 8-phase: 32*16 = 512 blocks = exactly 2 full rounds at 1 block/CU
  gemm8_nt<3, true><<<dim3(512), 512, 0, stream>>>(hs_bf, WqkvT, Cqkv, 16, 32, 2048, 2048, 3072);

  rope_qkv<<<dim3(24, 128, 2), 256, 0, stream>>>(Cqkv, bq, bk, bv, cosp, sinp, q_r, k_r, v_r);

  transpose_bf16<<<dim3(4, 128, 8), tb, 0, stream>>>(k_r, k_rT, 4096, 128, 524288, 524288);
  transpose_bf16<<<dim3(4, 128, 8), tb, 0, stream>>>(v_r, v_rT, 4096, 128, 524288, 524288);

  // pk + pvT: split-K x4 into fp32 partials (reusing dead hs_bf region), then reduce
  float* part = (float*)hs_bf;  // 4 x 2097152 floats = 33.55 MB (fits exactly)
  gemm_pkpv<<<dim3(8, 16, 4), 256, 0, stream>>>(E_T, k_rT, v_rT, Fp_T, part);
  reduce4_bf16<<<2048, 256, 0, stream>>>(part, pk);

  attn_fused<<<dim3(32, 32), 256, 0, stream>>>(q_r, pk, pvT, attnb);

  // output projection -> fp32 out, 8-phase 256^2 (256 blocks = exactly 1 round)
  gemm8_nt<4, false><<<dim3(256), 512, 0, stream>>>(attnb, WoT, out, 8, 32, 2048, 2048, 2048);
}

// Round 10
// 510.340 us; speedup vs baseline: 1.3517x; 1.0060x over previous
//
#include <hip/hip_runtime.h>
#include <math.h>

#define B_ 2
#define S_ 4096
#define HID_ 2048
#define H_ 16
#define KV_ 4
#define HD_ 128
#define K_ 1024
#define GROUPS_ 4
#define SCALE_ 0.08838834764831845f

typedef __bf16 bf16x8 __attribute__((ext_vector_type(8)));
typedef float f32x4 __attribute__((ext_vector_type(4)));
typedef float f32x8 __attribute__((ext_vector_type(8)));
typedef float f32x16 __attribute__((ext_vector_type(16)));
typedef ushort u16x8 __attribute__((ext_vector_type(8)));

__device__ __forceinline__ ushort f2bf(float f) {
  union { float f; unsigned int u; } x; x.f = f;
  unsigned int u = x.u;
  u += 0x7FFFu + ((u >> 16) & 1u);
  return (ushort)(u >> 16);
}
__device__ __forceinline__ float bf2f(ushort s) {
  union { unsigned int u; float f; } x; x.u = ((unsigned int)s) << 16;
  return x.f;
}

// async global->LDS, 16B per lane; LDS dest = uniform base + lane*16 [m97/m104]
__device__ __forceinline__ void gld16(const ushort* g, ushort* l) {
  __builtin_amdgcn_global_load_lds((const __attribute__((address_space(1))) void*)g,
                                   (__attribute__((address_space(3))) void*)l, 16, 0, 0);
}

// ---------------- elementwise cast fp32 -> bf16 ----------------
__global__ void cast_f32_bf16(const float* __restrict__ in, ushort* __restrict__ out, long n) {
  long i = ((long)blockIdx.x * blockDim.x + threadIdx.x) * 4;
  if (i >= n) return;
  float4 v = *(const float4*)(in + i);
  ushort4 o;
  o.x = f2bf(v.x); o.y = f2bf(v.y); o.z = f2bf(v.z); o.w = f2bf(v.w);
  *(ushort4*)(out + i) = o;
}

// ---------------- ALL fp32->bf16 weight transposes in ONE launch ----------------
__global__ void transpose_all(const float* __restrict__ Wq, const float* __restrict__ Wk,
                              const float* __restrict__ Wv, const float* __restrict__ Wo,
                              const float* __restrict__ E, const float* __restrict__ Fp,
                              ushort* __restrict__ WqkvT, ushort* __restrict__ WoT,
                              ushort* __restrict__ E_T, ushort* __restrict__ Fp_T) {
  __shared__ float t[32][33];
  int id = blockIdx.x;
  const float* src; ushort* dst; int R, C;
  if (id < 4096)       { src = Wq; dst = WqkvT;           R = 2048; C = 2048; }
  else if (id < 5120)  { src = Wk; dst = WqkvT + 4194304; R = 2048; C = 512;  id -= 4096; }
  else if (id < 6144)  { src = Wv; dst = WqkvT + 5242880; R = 2048; C = 512;  id -= 5120; }
  else if (id < 10240) { src = Wo; dst = WoT;             R = 2048; C = 2048; id -= 6144; }
  else if (id < 14336) { src = E;  dst = E_T;             R = 4096; C = 1024; id -= 10240; }
  else                 { src = Fp; dst = Fp_T;            R = 4096; C = 1024; id -= 14336; }
  int tX = C >> 5;
  int c0 = (id % tX) * 32, r0 = (id / tX) * 32;
  int tx = threadIdx.x, ty = threadIdx.y;
#pragma unroll
  for (int i = 0; i < 4; i++)
    t[ty + i * 8][tx] = src[(long)(r0 + ty + i * 8) * C + c0 + tx];
  __syncthreads();
#pragma unroll
  for (int i = 0; i < 4; i++)
    dst[(long)(c0 + ty + i * 8) * R + r0 + tx] = f2bf(t[tx][ty + i * 8]);
}

// ---------------- tiled transpose bf16, batched (z=16 covers k_r||v_r in one launch) ----
__global__ void transpose_bf16(const ushort* __restrict__ in, ushort* __restrict__ out,
                               int R, int C, long sIn, long sOut) {
  __shared__ ushort t[32][34];
  in += (long)blockIdx.z * sIn;
  out += (long)blockIdx.z * sOut;
  int c0 = blockIdx.x * 32, r0 = blockIdx.y * 32;
  int tx = threadIdx.x, ty = threadIdx.y;
#pragma unroll
  for (int i = 0; i < 4; i++)
    t[ty + i * 8][tx] = in[(long)(r0 + ty + i * 8) * C + c0 + tx];
  __syncthreads();
#pragma unroll
  for (int i = 0; i < 4; i++)
    out[(long)(c0 + ty + i * 8) * R + r0 + tx] = t[tx][ty + i * 8];
}

// ---------------- RoPE + bias + layout, vectorized (short8/float8 per lane) ----------
// grid (24 heads, S/32, B); 8 lanes per row, each handles d = dt..dt+7 and d+64.
__global__ __launch_bounds__(256) void rope_qkv(
    const ushort* __restrict__ Cqkv,
    const float* __restrict__ bq, const float* __restrict__ bk,
    const float* __restrict__ bv,
    const float* __restrict__ cosp, const float* __restrict__ sinp,
    ushort* __restrict__ q_r, ushort* __restrict__ k_r, ushort* __restrict__ v_r) {
  int head = blockIdx.x;  // 0..23: 16 q heads, 4 k, 4 v
  int s = blockIdx.y * 32 + (threadIdx.x >> 3);
  int b = blockIdx.z;
  int dt = (threadIdx.x & 7) * 8;
  long cs = ((long)b * S_ + s) * HD_;
  f32x8 c1 = *(const f32x8*)(cosp + cs + dt);
  f32x8 c2 = *(const f32x8*)(cosp + cs + dt + 64);
  f32x8 s1 = *(const f32x8*)(sinp + cs + dt);
  f32x8 s2 = *(const f32x8*)(sinp + cs + dt + 64);
  long rowbase = ((long)b * S_ + s) * 3072;
  if (head < H_) {
    int h = head;
    long in = rowbase + h * HD_ + dt;
    u16x8 x1v = *(const u16x8*)(Cqkv + in);
    u16x8 x2v = *(const u16x8*)(Cqkv + in + 64);
    f32x8 b1 = *(const f32x8*)(bq + h * HD_ + dt);
    f32x8 b2 = *(const f32x8*)(bq + h * HD_ + dt + 64);
    u16x8 o1v, o2v;
#pragma unroll
    for (int j = 0; j < 8; j++) {
      float x1 = bf2f(x1v[j]) + b1[j];
      float x2 = bf2f(x2v[j]) + b2[j];
      o1v[j] = f2bf((x1 * c1[j] - x2 * s1[j]) * SCALE_);
      o2v[j] = f2bf((x2 * c2[j] + x1 * s2[j]) * SCALE_);
    }
    long ob = (((long)b * H_ + h) * S_ + s) * HD_ + dt;
    *(u16x8*)(q_r + ob) = o1v;
    *(u16x8*)(q_r + ob + 64) = o2v;
  } else if (head < H_ + KV_) {
    int kv = head - H_;
    long in = rowbase + 2048 + kv * HD_ + dt;
    u16x8 x1v = *(const u16x8*)(Cqkv + in);
    u16x8 x2v = *(const u16x8*)(Cqkv + in + 64);
    f32x8 b1 = *(const f32x8*)(bk + kv * HD_ + dt);
    f32x8 b2 = *(const f32x8*)(bk + kv * HD_ + dt + 64);
    u16x8 o1v, o2v;
#pragma unroll
    for (int j = 0; j < 8; j++) {
      float x1 = bf2f(x1v[j]) + b1[j];
      float x2 = bf2f(x2v[j]) + b2[j];
      o1v[j] = f2bf(x1 * c1[j] - x2 * s1[j]);
      o2v[j] = f2bf(x2 * c2[j] + x1 * s2[j]);
    }
    long ob = (((long)b * KV_ + kv) * S_ + s) * HD_ + dt;
    *(u16x8*)(k_r + ob) = o1v;
    *(u16x8*)(k_r + ob + 64) = o2v;
  } else {
    int kv = head - H_ - KV_;
    long in = rowbase + 2560 + kv * HD_ + dt;
    u16x8 x1v = *(const u16x8*)(Cqkv + in);
    u16x8 x2v = *(const u16x8*)(Cqkv + in + 64);
    f32x8 b1 = *(const f32x8*)(bv + kv * HD_ + dt);
    f32x8 b2 = *(const f32x8*)(bv + kv * HD_ + dt + 64);
    u16x8 o1v, o2v;
#pragma unroll
    for (int j = 0; j < 8; j++) {
      o1v[j] = f2bf(bf2f(x1v[j]) + b1[j]);
      o2v[j] = f2bf(bf2f(x2v[j]) + b2[j]);
    }
    long ob = (((long)b * KV_ + kv) * S_ + s) * HD_ + dt;
    *(u16x8*)(v_r + ob) = o1v;
    *(u16x8*)(v_r + ob + 64) = o2v;
  }
}

// ---------------- NT GEMM body (m97 structure + XOR swizzle) — kept for pkpv ----------------
template <int BM, int BN, bool OUT_BF16>
__device__ __forceinline__ void gemm_body(
    const ushort* __restrict__ Ab, const ushort* __restrict__ Bb, void* __restrict__ Cb,
    int bm, int bn, int k0, int k1, int ldA, int ldB, int ldC, float scale) {
  __shared__ alignas(16) ushort As[BM * 32];
  __shared__ alignas(16) ushort Bs[BN * 32];
  constexpr int MT = BM / 32, NT = BN / 32;
  const int tid = threadIdx.x;
  const int wv = tid >> 6, lane = tid & 63;
  const int quad = lane >> 4, l16 = lane & 15;
  const int wm = (wv >> 1) * (BM / 2);
  const int wn = (wv & 1) * (BN / 2);
  const int srow = lane >> 2;
  const int scp = lane & 3;
  f32x4 acc[MT][NT];
#pragma unroll
  for (int i = 0; i < MT; i++)
#pragma unroll
    for (int j = 0; j < NT; j++)
#pragma unroll
      for (int r = 0; r < 4; r++) acc[i][j][r] = 0.f;
  const int sw = quad ^ ((l16 >> 1) & 3);
  for (int kk = k0; kk < k1; kk += 32) {
    __syncthreads();
#pragma unroll
    for (int j = 0; j < BM / 64; j++) {
      int r0 = wv * (BM / 4) + j * 16;
      int row = r0 + srow;
      gld16(Ab + (long)(bm + row) * ldA + kk + (scp ^ ((row >> 1) & 3)) * 8, &As[r0 * 32]);
    }
#pragma unroll
    for (int j = 0; j < BN / 64; j++) {
      int r0 = wv * (BN / 4) + j * 16;
      int row = r0 + srow;
      gld16(Bb + (long)(bn + row) * ldB + kk + (scp ^ ((row >> 1) & 3)) * 8, &Bs[r0 * 32]);
    }
    __syncthreads();
    bf16x8 af[MT], bf[NT];
#pragma unroll
    for (int i = 0; i < MT; i++)
      af[i] = *(const bf16x8*)&As[(wm + i * 16 + l16) * 32 + sw * 8];
#pragma unroll
    for (int j = 0; j < NT; j++)
      bf[j] = *(const bf16x8*)&Bs[(wn + j * 16 + l16) * 32 + sw * 8];
#pragma unroll
    for (int i = 0; i < MT; i++)
#pragma unroll
      for (int j = 0; j < NT; j++)
        acc[i][j] = __builtin_amdgcn_mfma_f32_16x16x32_bf16(af[i], bf[j], acc[i][j], 0, 0, 0);
  }
#pragma unroll
  for (int i = 0; i < MT; i++)
#pragma unroll
    for (int j = 0; j < NT; j++)
#pragma unroll
      for (int r = 0; r < 4; r++) {
        long row = bm + wm + i * 16 + quad * 4 + r;
        long col = bn + wn + j * 16 + l16;
        float v = acc[i][j][r] * scale;
        if (OUT_BF16)
          ((ushort*)Cb)[row * ldC + col] = f2bf(v);
        else
          ((float*)Cb)[row * ldC + col] = v;
      }
}

// pk/pvT with split-K x4: fp32 partials. grid (8 tiles, 16 z, 4 kseg)
__global__ __launch_bounds__(256) void gemm_pkpv(
    const ushort* __restrict__ E_T, const ushort* __restrict__ k_rT,
    const ushort* __restrict__ v_rT, const ushort* __restrict__ Fp_T,
    float* __restrict__ part) {
  int z = blockIdx.y, ks = blockIdx.z;
  const ushort *A, *Bt;
  int bm, bn, ldC;
  if (z < 8) {  // pk[z] (K_,HD) = E_T @ k_rT[z]^T
    A = E_T; Bt = k_rT + (long)z * 524288;
    bm = blockIdx.x * 128; bn = 0; ldC = 128;
  } else {      // pvT[z-8] (HD,K_) = v_rT @ Fp_T^T
    A = v_rT + (long)(z - 8) * 524288; Bt = Fp_T;
    bm = 0; bn = blockIdx.x * 128; ldC = 1024;
  }
  float* Cb = part + (long)ks * 2097152 + (long)z * 131072;
  gemm_body<128, 128, false>(A, Bt, Cb, bm, bn, ks * 1024, ks * 1024 + 1024,
                             4096, 4096, ldC, 1.f);
}

// sum 4 fp32 partial slabs -> bf16 (pk||pvT contiguous)
__global__ void reduce4_bf16(const float* __restrict__ part, ushort* __restrict__ out) {
  long i = ((long)blockIdx.x * 256 + threadIdx.x) * 4;
  float4 a = *(const float4*)(part + i);
  float4 b = *(const float4*)(part + 2097152 + i);
  float4 c = *(const float4*)(part + 4194304 + i);
  float4 d = *(const float4*)(part + 6291456 + i);
  ushort4 o;
  o.x = f2bf(a.x + b.x + c.x + d.x);
  o.y = f2bf(a.y + b.y + c.y + d.y);
  o.z = f2bf(a.z + b.z + c.z + d.z);
  o.w = f2bf(a.w + b.w + c.w + d.w);
  *(ushort4*)(out + i) = o;
}

// ---------------- 256 x (NB*64) 8-phase NT GEMM (T2+T3+T4+T5), relaxed publish ----------
template <int NB, bool OUT_BF16>
__global__ __launch_bounds__(512, 2) void gemm8_nt(
    const ushort* __restrict__ Ab, const ushort* __restrict__ Bb, void* __restrict__ Cb,
    int ntn, int NT, int ldA, int ldB, int ldC) {
  __shared__ alignas(16) ushort As[2][256 * 64];        // 64 KB
  __shared__ alignas(16) ushort Bs[2][NB * 64 * 64];    // NB*16 KB
  const int nwg = gridDim.x;
  const int cpx = nwg >> 3;  // blocks per XCD (grids are %8==0)
  const int bid = blockIdx.x;
  const int swz = (bid & 7) * cpx + (bid >> 3);  // XCD-contiguous chunks (T1, bijective)
  const int bm = (swz / ntn) * 256, bn = (swz % ntn) * (NB * 64);
  const int tid = threadIdx.x;
  const int wv = tid >> 6, lane = tid & 63;
  const int quad = lane >> 4, l16 = lane & 15, l7 = l16 & 7;
  const int wm2 = wv >> 2, wn4 = wv & 3;
  const int ida = wn4;
  const int ha = wm2;
  const int lrow = lane >> 3, lchk = lane & 7;
  const int schk = (lchk ^ lrow) * 8;  // pre-swizzled source chunk (rule 21)

  auto stageBown = [&](int buf, int kt) {
#pragma unroll
    for (int j = 0; j < NB; j++) {
      int rloc = wn4 * (NB * 16) + j * 16 + wm2 * 8;
      int r = rloc + lrow;
      gld16(Bb + (long)(bn + r) * ldB + kt * 64 + schk, &Bs[buf][rloc * 64]);
    }
  };
  auto stageA = [&](int buf, int kt, int sp) {
#pragma unroll
    for (int j = 0; j < 2; j++) {
      int rloc = ha * 128 + sp * 64 + j * 32 + ida * 8;
      int r = rloc + lrow;
      gld16(Ab + (long)(bm + r) * ldA + kt * 64 + schk, &As[buf][rloc * 64]);
    }
  };
  auto rdA = [&](int buf, int m, int ks) -> bf16x8 {
    int ra = wm2 * 128 + m * 16 + l16;
    int c = (ks * 4 + quad) ^ l7;
    return *(const bf16x8*)&As[buf][ra * 64 + c * 8];
  };
  auto rdB = [&](int buf, int n, int ks) -> bf16x8 {
    int rb = wn4 * (NB * 16) + n * 16 + l16;
    int c = (ks * 4 + quad) ^ l7;
    return *(const bf16x8*)&Bs[buf][rb * 64 + c * 8];
  };

  f32x4 acc[8][NB];
#pragma unroll
  for (int m = 0; m < 8; m++)
#pragma unroll
    for (int n = 0; n < NB; n++)
#pragma unroll
      for (int r = 0; r < 4; r++) acc[m][n][r] = 0.f;

  stageBown(0, 0); stageA(0, 0, 0); stageA(0, 0, 1);
  asm volatile("s_waitcnt vmcnt(2)" ::: "memory");
  __builtin_amdgcn_s_barrier();

#pragma unroll 2
  for (int t = 0; t < NT - 1; ++t) {
    const int cur = t & 1, nxt = cur ^ 1;
    const int kt1 = t + 1;
    bf16x8 b[NB][2], x0[2], x1[2];
#pragma unroll
    for (int n = 0; n < NB; n++) { b[n][0] = rdB(cur, n, 0); b[n][1] = rdB(cur, n, 1); }
    x0[0] = rdA(cur, 0, 0); x0[1] = rdA(cur, 0, 1);
    x1[0] = rdA(cur, 1, 0); x1[1] = rdA(cur, 1, 1);
    stageBown(nxt, kt1);
    __builtin_amdgcn_s_barrier();
    asm volatile("s_waitcnt lgkmcnt(0)" ::: "memory");
    __builtin_amdgcn_s_setprio(1);
#pragma unroll
    for (int n = 0; n < NB; n++)
#pragma unroll
      for (int ks = 0; ks < 2; ks++) {
        acc[0][n] = __builtin_amdgcn_mfma_f32_16x16x32_bf16(x0[ks], b[n][ks], acc[0][n], 0, 0, 0);
        acc[1][n] = __builtin_amdgcn_mfma_f32_16x16x32_bf16(x1[ks], b[n][ks], acc[1][n], 0, 0, 0);
      }
    __builtin_amdgcn_s_setprio(0);
    __builtin_amdgcn_s_barrier();
    x0[0] = rdA(cur, 2, 0); x0[1] = rdA(cur, 2, 1);
    x1[0] = rdA(cur, 3, 0); x1[1] = rdA(cur, 3, 1);
    stageA(nxt, kt1, 0);
    if constexpr (NB == 3) asm volatile("s_waitcnt vmcnt(5)" ::: "memory");
    else                   asm volatile("s_waitcnt vmcnt(6)" ::: "memory");
    __builtin_amdgcn_s_barrier();
    asm volatile("s_waitcnt lgkmcnt(0)" ::: "memory");
    __builtin_amdgcn_s_setprio(1);
#pragma unroll
    for (int n = 0; n < NB; n++)
#pragma unroll
      for (int ks = 0; ks < 2; ks++) {
        acc[2][n] = __builtin_amdgcn_mfma_f32_16x16x32_bf16(x0[ks], b[n][ks], acc[2][n], 0, 0, 0);
        acc[3][n] = __builtin_amdgcn_mfma_f32_16x16x32_bf16(x1[ks], b[n][ks], acc[3][n], 0, 0, 0);
      }
    __builtin_amdgcn_s_setprio(0);
    __builtin_amdgcn_s_barrier();
    x0[0] = rdA(cur, 4, 0); x0[1] = rdA(cur, 4, 1);
    x1[0] = rdA(cur, 5, 0); x1[1] = rdA(cur, 5, 1);
    stageA(nxt, kt1, 1);
    __builtin_amdgcn_s_barrier();
    asm volatile("s_waitcnt lgkmcnt(0)" ::: "memory");
    __builtin_amdgcn_s_setprio(1);
#pragma unroll
    for (int n = 0; n < NB; n++)
#pragma unroll
      for (int ks = 0; ks < 2; ks++) {
        acc[4][n] = __builtin_amdgcn_mfma_f32_16x16x32_bf16(x0[ks], b[n][ks], acc[4][n], 0, 0, 0);
        acc[5][n] = __builtin_amdgcn_mfma_f32_16x16x32_bf16(x1[ks], b[n][ks], acc[5][n], 0, 0, 0);
      }
    __builtin_amdgcn_s_setprio(0);
    __builtin_amdgcn_s_barrier();
    x0[0] = rdA(cur, 6, 0); x0[1] = rdA(cur, 6, 1);
    x1[0] = rdA(cur, 7, 0); x1[1] = rdA(cur, 7, 1);
    asm volatile("s_waitcnt vmcnt(2)" ::: "memory");
    __builtin_amdgcn_s_barrier();
    asm volatile("s_waitcnt lgkmcnt(0)" ::: "memory");
    __builtin_amdgcn_s_setprio(1);
#pragma unroll
    for (int n = 0; n < NB; n++)
#pragma unroll
      for (int ks = 0; ks < 2; ks++) {
        acc[6][n] = __builtin_amdgcn_mfma_f32_16x16x32_bf16(x0[ks], b[n][ks], acc[6][n], 0, 0, 0);
        acc[7][n] = __builtin_amdgcn_mfma_f32_16x16x32_bf16(x1[ks], b[n][ks], acc[7][n], 0, 0, 0);
      }
    __builtin_amdgcn_s_setprio(0);
    __builtin_amdgcn_s_barrier();
  }

  {
    const int cur = (NT - 1) & 1;
    asm volatile("s_waitcnt vmcnt(0)" ::: "memory");
    __builtin_amdgcn_s_barrier();
    bf16x8 b[NB][2];
#pragma unroll
    for (int n = 0; n < NB; n++) { b[n][0] = rdB(cur, n, 0); b[n][1] = rdB(cur, n, 1); }
#pragma unroll
    for (int m = 0; m < 8; m++) {
      bf16x8 a0 = rdA(cur, m, 0), a1 = rdA(cur, m, 1);
#pragma unroll
      for (int n = 0; n < NB; n++) {
        acc[m][n] = __builtin_amdgcn_mfma_f32_16x16x32_bf16(a0, b[n][0], acc[m][n], 0, 0, 0);
        acc[m][n] = __builtin_amdgcn_mfma_f32_16x16x32_bf16(a1, b[n][1], acc[m][n], 0, 0, 0);
      }
    }
  }

#pragma unroll
  for (int m = 0; m < 8; m++)
#pragma unroll
    for (int n = 0; n < NB; n++)
#pragma unroll
      for (int r = 0; r < 4; r++) {
        long row = bm + wm2 * 128 + m * 16 + quad * 4 + r;
        long col = bn + wn4 * (NB * 16) + n * 16 + l16;
        if (OUT_BF16)
          ((ushort*)Cb)[row * ldC + col] = f2bf(acc[m][n][r]);
        else
          ((float*)Cb)[row * ldC + col] = acc[m][n][r];
      }
}

// ---------------- fused attention v5.1: swapped-QK 32x32, LDS-staged, XCD-local KV ----
// Grid SWAPPED to (x=bh, y=s-tile): XCD = linear%8 = bh%8 -> each XCD's KV working
// set is 4 (b,kvh) pairs = 2 MB (L2-resident) instead of all 8 groups = 4.2 MB
// (thrash). Staging latency L3->L2. Kernel otherwise identical to verified v5.
__device__ __forceinline__ void stage_chunk(const ushort* __restrict__ pkb,
                                            const ushort* __restrict__ pvb,
                                            ushort* __restrict__ bk, ushort* __restrict__ bv,
                                            int k0, int wv, int lane) {
  const int sr4 = lane >> 4, cp16 = lane & 15;  // pk staging: 4 rows x 16 chunks
  const int sr8 = lane >> 3, cp8 = lane & 7;    // pv staging: 8 rows x 8 chunks
#pragma unroll
  for (int j = 0; j < 4; j++) {  // pk rows k0 + wv*16+j*4 .. +3
    int kr = wv * 16 + j * 4 + sr4;
    gld16(pkb + (long)(k0 + kr) * HD_ + (cp16 ^ (kr & 7)) * 8, bk + (wv * 16 + j * 4) * HD_);
  }
#pragma unroll
  for (int j = 0; j < 4; j++) {  // pv rows (hd) wv*32+j*8 .. +7
    int hd = wv * 32 + j * 8 + sr8;
    gld16(pvb + (long)hd * K_ + k0 + (cp8 ^ (hd & 7)) * 8, bv + (wv * 32 + j * 8) * 64);
  }
}

__global__ __launch_bounds__(256, 2) void attn_fused(
    const ushort* __restrict__ q_r,   // (B,H,S,HD), pre-scaled
    const ushort* __restrict__ pk,    // (B,KV,K,HD)
    const ushort* __restrict__ pvT,   // (B,KV,HD,K)
    ushort* __restrict__ attn) {      // (B,S,H*HD)
  __shared__ alignas(16) ushort Bk[2][64 * HD_];   // 32 KB (double-buffered)
  __shared__ alignas(16) ushort Bv[2][HD_ * 64];   // 32 KB (double-buffered)
  const int bh = blockIdx.x;          // SWAPPED: bh on x -> XCD = bh%8
  const int b = bh >> 4, h = bh & 15;
  const int kvh = h >> 2;
  const int wv = threadIdx.x >> 6, lane = threadIdx.x & 63;
  const int l31 = lane & 31, hi = lane >> 5, k7 = l31 & 7;
  const int s0 = blockIdx.y * 128 + wv * 32;

  const ushort* pkb = pk + ((long)b * KV_ + kvh) * (K_ * HD_);
  const ushort* pvb = pvT + ((long)b * KV_ + kvh) * (HD_ * K_);

  // Q as B-operand frags: lane holds Q[s0+l31][s*16 + hi*8 .. +7]
  bf16x8 qb[8];
#pragma unroll
  for (int s = 0; s < 8; s++)
    qb[s] = *(const bf16x8*)(q_r + (((long)b * H_ + h) * S_ + s0 + l31) * HD_ + s * 16 + hi * 8);

  f32x16 O[4];
#pragma unroll
  for (int t = 0; t < 4; t++)
#pragma unroll
    for (int r = 0; r < 16; r++) O[t][r] = 0.f;
  float lsum = 0.f;  // partial row-sum for q = l31 (this lane's half of k)

  constexpr int NC = K_ / 64;

  // prologue: stage chunk 0; __syncthreads drains vmcnt -> visible
  stage_chunk(pkb, pvb, &Bk[0][0], &Bv[0][0], 0, wv, lane);
  __syncthreads();

  for (int c = 0; c < NC; c++) {
    const int cur = c & 1;
    if (c + 1 < NC)
      stage_chunk(pkb, pvb, &Bk[cur ^ 1][0], &Bv[cur ^ 1][0], (c + 1) * 64, wv, lane);

    const ushort* bkc = &Bk[cur][0];
    const ushort* bvc = &Bv[cur][0];

    // QK^T swapped: pacc[m] = K[32m..32m+31][:] x Q^T -> P[k][q], col q = l31
    f32x16 pacc0, pacc1;
#pragma unroll
    for (int r = 0; r < 16; r++) { pacc0[r] = 0.f; pacc1[r] = 0.f; }
    __builtin_amdgcn_s_setprio(1);
#pragma unroll
    for (int s = 0; s < 8; s++) {
      int cc = ((2 * s + hi) ^ k7) * 8;
      bf16x8 k0 = *(const bf16x8*)&bkc[l31 * HD_ + cc];
      bf16x8 k1 = *(const bf16x8*)&bkc[(32 + l31) * HD_ + cc];
      pacc0 = __builtin_amdgcn_mfma_f32_32x32x16_bf16(k0, qb[s], pacc0, 0, 0, 0);
      pacc1 = __builtin_amdgcn_mfma_f32_32x32x16_bf16(k1, qb[s], pacc1, 0, 0, 0);
    }
    __builtin_amdgcn_s_setprio(0);

    // softmax (no-max: exp(s-12)) fully in-register
#pragma unroll
    for (int r = 0; r < 16; r++) {
      pacc0[r] = __expf(pacc0[r] - 12.f);
      pacc1[r] = __expf(pacc1[r] - 12.f);
      lsum += pacc0[r] + pacc1[r];
    }

    // P -> A-frags: 16 cvt_pk + 8 permlane32_swap (s' = 2m+e)
    bf16x8 paf[4];
#pragma unroll
    for (int m = 0; m < 2; m++) {
#pragma unroll
      for (int e = 0; e < 2; e++) {
        float v0 = m ? pacc1[8 * e + 0] : pacc0[8 * e + 0];
        float v1 = m ? pacc1[8 * e + 1] : pacc0[8 * e + 1];
        float v2 = m ? pacc1[8 * e + 2] : pacc0[8 * e + 2];
        float v3 = m ? pacc1[8 * e + 3] : pacc0[8 * e + 3];
        float v4 = m ? pacc1[8 * e + 4] : pacc0[8 * e + 4];
        float v5 = m ? pacc1[8 * e + 5] : pacc0[8 * e + 5];
        float v6 = m ? pacc1[8 * e + 6] : pacc0[8 * e + 6];
        float v7 = m ? pacc1[8 * e + 7] : pacc0[8 * e + 7];
        unsigned int A0, A1, B0, B1;
        asm("v_cvt_pk_bf16_f32 %0, %1, %2" : "=v"(A0) : "v"(v0), "v"(v1));
        asm("v_cvt_pk_bf16_f32 %0, %1, %2" : "=v"(A1) : "v"(v2), "v"(v3));
        asm("v_cvt_pk_bf16_f32 %0, %1, %2" : "=v"(B0) : "v"(v4), "v"(v5));
        asm("v_cvt_pk_bf16_f32 %0, %1, %2" : "=v"(B1) : "v"(v6), "v"(v7));
        asm("v_permlane32_swap_b32 %0, %1" : "+v"(A0), "+v"(B0));
        asm("v_permlane32_swap_b32 %0, %1" : "+v"(A1), "+v"(B1));
        union { unsigned int u[4]; bf16x8 v; } w;
        w.u[0] = A0; w.u[1] = A1; w.u[2] = B0; w.u[3] = B1;
        paf[2 * m + e] = w.v;
      }
    }

    // PV: O[ht] += P(32q x 16k) x V^T-frag(16k x 32hd)
    __builtin_amdgcn_s_setprio(1);
#pragma unroll
    for (int sp = 0; sp < 4; sp++) {
#pragma unroll
      for (int ht = 0; ht < 4; ht++) {
        int vr = ht * 32 + l31;
        bf16x8 vb = *(const bf16x8*)&bvc[vr * 64 + (((2 * sp + hi) ^ (vr & 7)) * 8)];
        O[ht] = __builtin_amdgcn_mfma_f32_32x32x16_bf16(paf[sp], vb, O[ht], 0, 0, 0);
      }
    }
    __builtin_amdgcn_s_setprio(0);

    __syncthreads();
  }

  // finalize: full row-sum for q=l31, then per-reg inverse via shfl
  lsum += __shfl_xor(lsum, 32);
  float inv_own = 1.f / lsum;
#pragma unroll
  for (int r = 0; r < 16; r++) {
    int q = (r & 3) + 8 * (r >> 2) + 4 * hi;
    float invq = __shfl(inv_own, q);
    long row = (long)b * S_ + s0 + q;
#pragma unroll
    for (int ht = 0; ht < 4; ht++)
      attn[row * (long)HID_ + h * HD_ + ht * 32 + l31] = f2bf(O[ht][r] * invq);
  }
}

// ---------------- host ----------------
extern "C" void kernel_launch(void* const* d_in, const int* in_sizes, int n_in,
                              void* d_out, int out_size, void* d_ws, size_t ws_size,
                              hipStream_t stream) {
  const float* hs = (const float*)d_in[0];
  const float* cosp = (const float*)d_in[1];
  const float* sinp = (const float*)d_in[2];
  // d_in[3] attention_mask: uniform over softmax axis -> provably a no-op
  const float* Wq = (const float*)d_in[4];
  const float* bq = (const float*)d_in[5];
  const float* Wk = (const float*)d_in[6];
  const float* bk = (const float*)d_in[7];
  const float* Wv = (const float*)d_in[8];
  const float* bv = (const float*)d_in[9];
  const float* Wo = (const float*)d_in[10];
  const float* E = (const float*)d_in[11];
  const float* Fp = (const float*)d_in[12];
  float* out = (float*)d_out;

  ushort* w = (ushort*)d_ws;
  ushort* hs_bf = w;            w += 16777216;  // (8192,2048); later: fp32 pkpv partials
  ushort* WqkvT = w;            w += 6291456;   // (3072,2048)
  ushort* WoT = w;              w += 4194304;   // (2048,2048)
  ushort* E_T = w;              w += 4194304;   // (1024,4096)
  ushort* Fp_T = w;             w += 4194304;   // (1024,4096)
  ushort* Cqkv = w;             w += 25165824;  // (8192,3072)
  ushort* q_r = w;              w += 16777216;  // (B,H,S,HD)
  ushort* k_r = w;              w += 4194304;   // (B,KV,S,HD)  — contiguous with v_r!
  ushort* v_r = w;              w += 4194304;
  ushort* k_rT = w;             w += 4194304;   // (B,KV,HD,S)  — contiguous with v_rT!
  ushort* v_rT = w;             w += 4194304;
  ushort* pk = w;               w += 1048576;   // (B,KV,K,HD)  — contiguous with pvT!
  ushort* pvT = w;              w += 1048576;   // (B,KV,HD,K)
  ushort* attnb = Cqkv;  // alias: Cqkv dead after rope_qkv

  dim3 tb(32, 8);
  cast_f32_bf16<<<16384, 256, 0, stream>>>(hs, hs_bf, 16777216L);
  transpose_all<<<18432, tb, 0, stream>>>(Wq, Wk, Wv, Wo, E, Fp, WqkvT, WoT, E_T, Fp_T);

  // fused QKV projection: (8192,2048) @ (3072,2048)^T -> (8192,3072)
  // 256x192 8-phase: 32*16 = 512 blocks = exactly 2 full rounds at 1 block/CU
  gemm8_nt<3, true><<<dim3(512), 512, 0, stream>>>(hs_bf, WqkvT, Cqkv, 16, 32, 2048, 2048, 3072);

  rope_qkv<<<dim3(24, 128, 2), 256, 0, stream>>>(Cqkv, bq, bk, bv, cosp, sinp, q_r, k_r, v_r);

  // ONE launch transposes k_r||v_r (contiguous) -> k_rT||v_rT (contiguous)
  transpose_bf16<<<dim3(4, 128, 16), tb, 0, stream>>>(k_r, k_rT, 4096, 128, 524288, 524288);

  // pk + pvT: split-K x4 into fp32 partials (reusing dead hs_bf region), then reduce
  float* part = (float*)hs_bf;  // 4 x 2097152 floats = 33.55 MB (fits exactly)
  gemm_pkpv<<<dim3(8, 16, 4), 256, 0, stream>>>(E_T, k_rT, v_rT, Fp_T, part);
  reduce4_bf16<<<2048, 256, 0, stream>>>(part, pk);

  // grid swapped: x=bh (XCD locality), y=s-tile
  attn_fused<<<dim3(32, 32), 256, 0, stream>>>(q_r, pk, pvT, attnb);

  // output projection -> fp32 out, 8-phase 256^2 (256 blocks = exactly 1 round)
  gemm8_nt<4, false><<<dim3(256), 512, 0, stream>>>(attnb, WoT, out, 8, 32, 2048, 2048, 2048);
}